// Round 1
// baseline (425.003 us; speedup 1.0000x reference)
//
#include <hip/hip_runtime.h>
#include <hip/hip_bf16.h>

// Problem constants: B=2, T=1024, D=1024, N=16
#define TT 1024
#define BB 2
#define DD 1024
#define NN 16
#define NCH 32   // chunks
#define LCH 32   // chunk length (NCH*LCH == TT)

#define K_STEEP 10.0f
#define V_TH_MIN 0.1f
#define L2E 1.44269504088896f

// ---------------------------------------------------------------------------
// Tiled fp32 GEMM: C[M][N] = A[M][K] @ B[K][N]  (+ epilogue)
// EPI 0: plain store
// EPI 1: softplus(v + bias[col])
// EPI 2: v - sub[row*ldc + col]
// BM=64, BN=128, BK=16, 256 threads, 4x8 per thread.
// ---------------------------------------------------------------------------
template<int EPI>
__global__ __launch_bounds__(256) void gemm_f32(
    const float* __restrict__ A, int lda,
    const float* __restrict__ Bw, int ldb,
    float* __restrict__ C, int ldc,
    int M, int Ncols, int K,
    const float* __restrict__ bias,
    const float* __restrict__ sub)
{
    const int BM = 64, BN = 128, BK = 16;
    __shared__ float As[BK][BM];
    __shared__ float Bs[BK][BN];

    int tid = threadIdx.x;
    int bn = blockIdx.x * BN;
    int bm = blockIdx.y * BM;
    int tx = tid & 15;   // 0..15 -> col group (8 cols)
    int ty = tid >> 4;   // 0..15 -> row group (4 rows)

    float acc[4][8];
    #pragma unroll
    for (int i = 0; i < 4; i++)
        #pragma unroll
        for (int j = 0; j < 8; j++) acc[i][j] = 0.f;

    int arow = tid >> 2;          // 0..63
    int kslot = (tid & 3) * 4;    // 0,4,8,12

    for (int k0 = 0; k0 < K; k0 += BK) {
        // A tile: 64x16, one float4 per thread (along k)
        float4 av = *(const float4*)(A + (size_t)(bm + arow) * lda + k0 + kslot);
        As[kslot + 0][arow] = av.x;
        As[kslot + 1][arow] = av.y;
        As[kslot + 2][arow] = av.z;
        As[kslot + 3][arow] = av.w;
        // B tile: 16x128, two float4 per thread (along n)
        #pragma unroll
        for (int u = 0; u < 2; u++) {
            int idx = tid + u * 256;
            int n4 = (idx & 31) * 4;
            int krow = idx >> 5;
            *(float4*)&Bs[krow][n4] =
                *(const float4*)(Bw + (size_t)(k0 + krow) * ldb + bn + n4);
        }
        __syncthreads();
        #pragma unroll
        for (int k = 0; k < BK; k++) {
            float4 ra = *(const float4*)&As[k][ty * 4];
            float rb[8];
            *(float4*)&rb[0] = *(const float4*)&Bs[k][tx * 8];
            *(float4*)&rb[4] = *(const float4*)&Bs[k][tx * 8 + 4];
            float a0 = ra.x, a1 = ra.y, a2 = ra.z, a3 = ra.w;
            #pragma unroll
            for (int j = 0; j < 8; j++) {
                acc[0][j] = fmaf(a0, rb[j], acc[0][j]);
                acc[1][j] = fmaf(a1, rb[j], acc[1][j]);
                acc[2][j] = fmaf(a2, rb[j], acc[2][j]);
                acc[3][j] = fmaf(a3, rb[j], acc[3][j]);
            }
        }
        __syncthreads();
    }

    // epilogue + vectorized store
    #pragma unroll
    for (int i = 0; i < 4; i++) {
        int row = bm + ty * 4 + i;
        int colb = bn + tx * 8;
        float v[8];
        #pragma unroll
        for (int j = 0; j < 8; j++) {
            float x = acc[i][j];
            if (EPI == 1) {
                x += bias[colb + j];
                // softplus: max(x,0) + log1p(exp(-|x|))
                x = fmaxf(x, 0.f) + log1pf(__expf(-fabsf(x)));
            }
            if (EPI == 2) {
                x -= sub[(size_t)row * ldc + colb + j];
            }
            v[j] = x;
        }
        *(float4*)&C[(size_t)row * ldc + colb] = *(float4*)&v[0];
        *(float4*)&C[(size_t)row * ldc + colb + 4] = *(float4*)&v[4];
    }
}

// ---------------------------------------------------------------------------
// Bm/Cm: bc[row][0:16] = H[row] @ W_B ; bc[row][16:32] = H[row] @ W_C
// block per row, 256 threads.
// ---------------------------------------------------------------------------
__global__ __launch_bounds__(256) void bc_kernel(
    const float* __restrict__ H,
    const float* __restrict__ W_B,
    const float* __restrict__ W_C,
    float* __restrict__ bc)
{
    int row = blockIdx.x;
    int tid = threadIdx.x;
    __shared__ float hrow[DD];
    for (int i = tid; i < DD; i += 256) hrow[i] = H[(size_t)row * DD + i];
    __syncthreads();
    int n = tid >> 3;   // 0..31
    int j = tid & 7;    // 0..7
    const float* W = (n < 16) ? (W_B + n) : (W_C + (n - 16));
    float acc = 0.f;
    for (int k = j; k < DD; k += 8) acc = fmaf(hrow[k], W[(size_t)k * NN], acc);
    acc += __shfl_xor(acc, 1);
    acc += __shfl_xor(acc, 2);
    acc += __shfl_xor(acc, 4);
    if (j == 0) bc[(size_t)row * 32 + n] = acc;
}

// ---------------------------------------------------------------------------
// Phase 1: per (b,d,chunk) local scan with s0=0.
// Outputs: Lst[c][b][d][n] (final local state), sdt[c][b][d] (sum of dt).
// ---------------------------------------------------------------------------
__global__ __launch_bounds__(256) void scan_phase1(
    const float* __restrict__ xz,     // [2048][2048]
    const float* __restrict__ dtb,    // [2048][1024] (post-softplus)
    const float* __restrict__ bc,     // [2048][32]
    const float* __restrict__ A_log,  // [1024][16]
    float* __restrict__ Lst,
    float* __restrict__ sdt)
{
    int tid = threadIdx.x;
    int d = blockIdx.x * 256 + tid;
    int b = blockIdx.y;
    int c = blockIdx.z;

    __shared__ float sBm[LCH][NN];
    for (int i = tid; i < LCH * NN; i += 256) {
        int j = i >> 4, n = i & 15;
        int r = b * TT + c * LCH + j;
        sBm[j][n] = bc[(size_t)r * 32 + n];
    }
    __syncthreads();

    float a2[NN];
    #pragma unroll
    for (int n = 0; n < NN; n++)
        a2[n] = -__expf(A_log[(size_t)d * NN + n]) * L2E;

    float s[NN];
    #pragma unroll
    for (int n = 0; n < NN; n++) s[n] = 0.f;

    float sum_dt = 0.f;
    for (int j = 0; j < LCH; j++) {
        int r = b * TT + c * LCH + j;
        float dt = dtb[(size_t)r * DD + d];
        float x  = xz[(size_t)r * (2 * DD) + d];
        float dtx = dt * x;
        sum_dt += dt;
        #pragma unroll
        for (int n = 0; n < NN; n++) {
            float dec = exp2f(a2[n] * dt);
            s[n] = fmaf(dec, s[n], dtx * sBm[j][n]);
        }
    }
    size_t base = ((size_t)(c * BB + b) * DD + d) * NN;
    #pragma unroll
    for (int n = 0; n < NN; n++) Lst[base + n] = s[n];
    sdt[(size_t)(c * BB + b) * DD + d] = sum_dt;
}

// ---------------------------------------------------------------------------
// Phase 2: combine chunk boundaries. thread per (b,d,n).
// Sinit[c] = chunk-initial state; S_{c} = L_{c-1} + exp(A*sdt_{c-1})*S_{c-1}
// ---------------------------------------------------------------------------
__global__ __launch_bounds__(256) void scan_phase2(
    const float* __restrict__ A_log,
    const float* __restrict__ Lst,
    const float* __restrict__ sdt,
    float* __restrict__ Sinit)
{
    int g = blockIdx.x * 256 + threadIdx.x;   // 0..32767
    int n = g & 15;
    int d = (g >> 4) & (DD - 1);
    int b = g >> 14;
    float a2 = -__expf(A_log[(size_t)d * NN + n]) * L2E;
    float s = 0.f;
    for (int c = 0; c < NCH; c++) {
        size_t idx = ((size_t)(c * BB + b) * DD + d) * NN + n;
        Sinit[idx] = s;
        float P = exp2f(a2 * sdt[(size_t)(c * BB + b) * DD + d]);
        s = fmaf(P, s, Lst[idx]);
    }
}

// ---------------------------------------------------------------------------
// Phase 3: replay chunk with correct initial state, produce gated output
// g = y_sp * silu(z), with y = scan_out + D_skip*x, spike gate fused.
// ---------------------------------------------------------------------------
__global__ __launch_bounds__(256) void scan_phase3(
    const float* __restrict__ xz,
    const float* __restrict__ dtb,
    const float* __restrict__ bc,
    const float* __restrict__ A_log,
    const float* __restrict__ Sinit,
    const float* __restrict__ D_skip,
    const float* __restrict__ v_th,
    float* __restrict__ gout)
{
    int tid = threadIdx.x;
    int d = blockIdx.x * 256 + tid;
    int b = blockIdx.y;
    int c = blockIdx.z;

    __shared__ float sB[LCH][NN];
    __shared__ float sC[LCH][NN];
    for (int i = tid; i < LCH * 32; i += 256) {
        int j = i >> 5, m = i & 31;
        int r = b * TT + c * LCH + j;
        float v = bc[(size_t)r * 32 + m];
        if (m < 16) sB[j][m] = v; else sC[j][m - 16] = v;
    }
    __syncthreads();

    float a2[NN];
    #pragma unroll
    for (int n = 0; n < NN; n++)
        a2[n] = -__expf(A_log[(size_t)d * NN + n]) * L2E;

    size_t base = ((size_t)(c * BB + b) * DD + d) * NN;
    float s[NN];
    #pragma unroll
    for (int n = 0; n < NN; n++) s[n] = Sinit[base + n];

    float dsk = D_skip[d];
    float vth = fmaxf(v_th[d], V_TH_MIN);

    for (int j = 0; j < LCH; j++) {
        int r = b * TT + c * LCH + j;
        float dt = dtb[(size_t)r * DD + d];
        float x  = xz[(size_t)r * (2 * DD) + d];
        float z  = xz[(size_t)r * (2 * DD) + DD + d];
        float dtx = dt * x;
        float y = 0.f;
        #pragma unroll
        for (int n = 0; n < NN; n++) {
            float dec = exp2f(a2[n] * dt);
            s[n] = fmaf(dec, s[n], dtx * sB[j][n]);
            y = fmaf(s[n], sC[j][n], y);
        }
        y = fmaf(dsk, x, y);
        float sp = 1.f / (1.f + __expf(-K_STEEP * (y - vth)));
        float sz = z / (1.f + __expf(-z));
        gout[(size_t)r * DD + d] = y * sp * sz;
    }
}

// ---------------------------------------------------------------------------
extern "C" void kernel_launch(void* const* d_in, const int* in_sizes, int n_in,
                              void* d_out, int out_size, void* d_ws, size_t ws_size,
                              hipStream_t stream) {
    const float* H      = (const float*)d_in[0];   // (2,1024,1024)
    const float* W_xz   = (const float*)d_in[1];   // (1024,2048)
    const float* W_dt   = (const float*)d_in[2];   // (1024,1024)
    const float* b_dt   = (const float*)d_in[3];   // (1024,)
    const float* A_log  = (const float*)d_in[4];   // (1024,16)
    const float* W_B    = (const float*)d_in[5];   // (1024,16)
    const float* W_C    = (const float*)d_in[6];   // (1024,16)
    const float* D_skip = (const float*)d_in[7];   // (1024,)
    const float* W_out  = (const float*)d_in[8];   // (1024,1024)
    const float* v_th   = (const float*)d_in[9];   // (1024,)
    float* out = (float*)d_out;

    float* ws  = (float*)d_ws;
    float* xz  = ws;                  // 2048*2048 = 4194304
    float* dtb = xz + 4194304;        // 2048*1024 = 2097152
    float* bcb = dtb + 2097152;       // 2048*32   = 65536
    float* gb  = bcb + 65536;         // 2048*1024 = 2097152
    float* Lst = gb + 2097152;        // 32*2*1024*16 = 1048576
    float* sdt = Lst + 1048576;       // 32*2*1024 = 65536
    float* Sin = sdt + 65536;         // 1048576

    const int M = BB * TT;  // 2048

    // 1) XZ = H @ W_xz
    gemm_f32<0><<<dim3(2 * DD / 128, M / 64), 256, 0, stream>>>(
        H, DD, W_xz, 2 * DD, xz, 2 * DD, M, 2 * DD, DD, nullptr, nullptr);
    // 2) dt = softplus(x @ W_dt + b_dt)   (x = first half of xz, lda=2048)
    gemm_f32<1><<<dim3(DD / 128, M / 64), 256, 0, stream>>>(
        xz, 2 * DD, W_dt, DD, dtb, DD, M, DD, DD, b_dt, nullptr);
    // 3) Bm|Cm
    bc_kernel<<<M, 256, 0, stream>>>(H, W_B, W_C, bcb);
    // 4) chunked scan
    scan_phase1<<<dim3(DD / 256, BB, NCH), 256, 0, stream>>>(
        xz, dtb, bcb, A_log, Lst, sdt);
    scan_phase2<<<(BB * DD * NN) / 256, 256, 0, stream>>>(A_log, Lst, sdt, Sin);
    scan_phase3<<<dim3(DD / 256, BB, NCH), 256, 0, stream>>>(
        xz, dtb, bcb, A_log, Sin, D_skip, v_th, gb);
    // 5) out = g @ W_out - H
    gemm_f32<2><<<dim3(DD / 128, M / 64), 256, 0, stream>>>(
        gb, DD, W_out, DD, out, DD, M, DD, DD, nullptr, H);
}

// Round 2
// 227.050 us; speedup vs baseline: 1.8719x; 1.8719x over previous
//
#include <hip/hip_runtime.h>
#include <hip/hip_bf16.h>
#include <stdint.h>

// Problem constants: B=2, T=1024, D=1024, N=16
#define TT 1024
#define BB 2
#define DD 1024
#define NN 16
#define NCH 32   // chunks
#define LCH 32   // chunk length (NCH*LCH == TT)

#define K_STEEP 10.0f
#define V_TH_MIN 0.1f
#define L2E 1.44269504088896f

typedef __bf16 bf16x8 __attribute__((ext_vector_type(8)));
typedef float f32x4 __attribute__((ext_vector_type(4)));

__device__ __forceinline__ short f2bf(float f) {
    union { float f; unsigned u; } c; c.f = f;
    unsigned r = (c.u + 0x7fffu + ((c.u >> 16) & 1u)) >> 16;
    return (short)r;
}

__device__ __forceinline__ void gload_lds16(const void* g, void* l) {
    __builtin_amdgcn_global_load_lds(
        (const __attribute__((address_space(1))) void*)g,
        (__attribute__((address_space(3))) void*)l, 16, 0, 0);
}

// ---------------------------------------------------------------------------
// bf16 MFMA GEMM (m97 structure): C[M][N] = A[M][K] @ BT[N][K]^T  (+ epilogue)
// A: M x K bf16 row-major.  BT: N x K bf16 row-major (i.e. B transposed).
// 128x128 tile, BK=32, 256 threads (4 waves, 2x2), 4x4 16x16x32 frags/wave.
// EPI 0: plain fp32 store
// EPI 1: softplus(v + bias[col])
// EPI 2: v - sub[row*ldc + col]
// ---------------------------------------------------------------------------
template<int EPI>
__global__ __launch_bounds__(256) void gemm_mfma(
    const short* __restrict__ A,
    const short* __restrict__ BT,
    float* __restrict__ C, int ldc,
    int M, int Ncols, int K,
    const float* __restrict__ bias,
    const float* __restrict__ sub)
{
    __shared__ short As[128 * 32];   // [row][k], 64B rows
    __shared__ short Bs[128 * 32];   // [n][k]

    const int tid = threadIdx.x;
    const int wave = tid >> 6, lane = tid & 63;
    const int bm = blockIdx.y * 128, bn = blockIdx.x * 128;
    const int wr = wave >> 1, wc = wave & 1;

    f32x4 acc[4][4] = {};

    const int kk = (lane >> 4) * 8;   // k-slot for frags
    const int r16 = lane & 15;

    for (int k0 = 0; k0 < K; k0 += 32) {
        // stage A,B tiles: 8192B each, 16B per lane-issue
        #pragma unroll
        for (int it = 0; it < 2; it++) {
            int off = wave * 2048 + it * 1024 + lane * 16;  // byte offset in tile
            int row = off >> 6;             // 64B per row (32 bf16)
            int ke  = (off & 63) >> 1;      // element offset in k
            gload_lds16(A + (size_t)(bm + row) * K + k0 + ke, (char*)As + off);
            gload_lds16(BT + (size_t)(bn + row) * K + k0 + ke, (char*)Bs + off);
        }
        __syncthreads();   // drains vmcnt before barrier (compiler-inserted)

        bf16x8 a[4], b[4];
        #pragma unroll
        for (int i = 0; i < 4; i++)
            a[i] = *(const bf16x8*)&As[(wr * 64 + i * 16 + r16) * 32 + kk];
        #pragma unroll
        for (int j = 0; j < 4; j++)
            b[j] = *(const bf16x8*)&Bs[(wc * 64 + j * 16 + r16) * 32 + kk];
        #pragma unroll
        for (int i = 0; i < 4; i++)
            #pragma unroll
            for (int j = 0; j < 4; j++)
                acc[i][j] = __builtin_amdgcn_mfma_f32_16x16x32_bf16(
                    a[i], b[j], acc[i][j], 0, 0, 0);
        __syncthreads();
    }

    // epilogue: C/D layout col = lane&15, row = (lane>>4)*4 + reg (m89/m91)
    #pragma unroll
    for (int i = 0; i < 4; i++) {
        #pragma unroll
        for (int j = 0; j < 4; j++) {
            #pragma unroll
            for (int g = 0; g < 4; g++) {
                int row = bm + wr * 64 + i * 16 + (lane >> 4) * 4 + g;
                int col = bn + wc * 64 + j * 16 + r16;
                float v = acc[i][j][g];
                if (EPI == 1) {
                    v += bias[col];
                    v = fmaxf(v, 0.f) + log1pf(__expf(-fabsf(v)));
                }
                if (EPI == 2) {
                    v -= sub[(size_t)row * ldc + col];
                }
                C[(size_t)row * ldc + col] = v;
            }
        }
    }
}

// ---------------------------------------------------------------------------
// fp32 -> bf16 plain convert (n multiple of 1024; grid covers n/4 threads)
// ---------------------------------------------------------------------------
__global__ __launch_bounds__(256) void convert_bf16(
    const float* __restrict__ in, short* __restrict__ out)
{
    int i = (blockIdx.x * 256 + threadIdx.x) * 4;
    float4 v = *(const float4*)&in[i];
    short4 o = { f2bf(v.x), f2bf(v.y), f2bf(v.z), f2bf(v.w) };
    *(short4*)&out[i] = o;
}

// extract x (first DD cols of xz, row stride 2*DD) -> bf16 [2048][1024]
__global__ __launch_bounds__(256) void convert_x(
    const float* __restrict__ xz, short* __restrict__ xb)
{
    int i = (blockIdx.x * 256 + threadIdx.x) * 4;
    int row = i >> 10, col = i & 1023;
    float4 v = *(const float4*)&xz[(size_t)row * (2 * DD) + col];
    short4 o = { f2bf(v.x), f2bf(v.y), f2bf(v.z), f2bf(v.w) };
    *(short4*)&xb[i] = o;
}

// ---------------------------------------------------------------------------
// fp32 W[K][N] -> bf16 WT[N][K] (transpose), 32x32 tiles
// ---------------------------------------------------------------------------
__global__ __launch_bounds__(256) void convert_transpose(
    const float* __restrict__ W, short* __restrict__ WT, int K, int N)
{
    __shared__ float t[32][33];
    int k0 = blockIdx.y * 32, n0 = blockIdx.x * 32;
    int r = threadIdx.x >> 3, q = threadIdx.x & 7;
    float4 v = *(const float4*)&W[(size_t)(k0 + r) * N + n0 + q * 4];
    t[r][q * 4 + 0] = v.x; t[r][q * 4 + 1] = v.y;
    t[r][q * 4 + 2] = v.z; t[r][q * 4 + 3] = v.w;
    __syncthreads();
    short4 o = { f2bf(t[q * 4 + 0][r]), f2bf(t[q * 4 + 1][r]),
                 f2bf(t[q * 4 + 2][r]), f2bf(t[q * 4 + 3][r]) };
    *(short4*)&WT[(size_t)(n0 + r) * K + k0 + q * 4] = o;
}

// ---------------------------------------------------------------------------
// Bm/Cm: bc[row][0:16] = H[row] @ W_B ; bc[row][16:32] = H[row] @ W_C
// ---------------------------------------------------------------------------
__global__ __launch_bounds__(256) void bc_kernel(
    const float* __restrict__ H,
    const float* __restrict__ W_B,
    const float* __restrict__ W_C,
    float* __restrict__ bc)
{
    int row = blockIdx.x;
    int tid = threadIdx.x;
    __shared__ float hrow[DD];
    for (int i = tid; i < DD; i += 256) hrow[i] = H[(size_t)row * DD + i];
    __syncthreads();
    int n = tid >> 3;
    int j = tid & 7;
    const float* W = (n < 16) ? (W_B + n) : (W_C + (n - 16));
    float acc = 0.f;
    for (int k = j; k < DD; k += 8) acc = fmaf(hrow[k], W[(size_t)k * NN], acc);
    acc += __shfl_xor(acc, 1);
    acc += __shfl_xor(acc, 2);
    acc += __shfl_xor(acc, 4);
    if (j == 0) bc[(size_t)row * 32 + n] = acc;
}

// ---------------------------------------------------------------------------
// Phase 1: per (b,d,chunk) local scan with s0=0.
// ---------------------------------------------------------------------------
__global__ __launch_bounds__(256) void scan_phase1(
    const float* __restrict__ xz,
    const float* __restrict__ dtb,
    const float* __restrict__ bc,
    const float* __restrict__ A_log,
    float* __restrict__ Lst,
    float* __restrict__ sdt)
{
    int tid = threadIdx.x;
    int d = blockIdx.x * 256 + tid;
    int b = blockIdx.y;
    int c = blockIdx.z;

    __shared__ float sBm[LCH][NN];
    for (int i = tid; i < LCH * NN; i += 256) {
        int j = i >> 4, n = i & 15;
        int r = b * TT + c * LCH + j;
        sBm[j][n] = bc[(size_t)r * 32 + n];
    }
    __syncthreads();

    float a2[NN];
    #pragma unroll
    for (int n = 0; n < NN; n++)
        a2[n] = -__expf(A_log[(size_t)d * NN + n]) * L2E;

    float s[NN];
    #pragma unroll
    for (int n = 0; n < NN; n++) s[n] = 0.f;

    float sum_dt = 0.f;
    for (int j = 0; j < LCH; j++) {
        int r = b * TT + c * LCH + j;
        float dt = dtb[(size_t)r * DD + d];
        float x  = xz[(size_t)r * (2 * DD) + d];
        float dtx = dt * x;
        sum_dt += dt;
        #pragma unroll
        for (int n = 0; n < NN; n++) {
            float dec = exp2f(a2[n] * dt);
            s[n] = fmaf(dec, s[n], dtx * sBm[j][n]);
        }
    }
    size_t base = ((size_t)(c * BB + b) * DD + d) * NN;
    #pragma unroll
    for (int n = 0; n < NN; n++) Lst[base + n] = s[n];
    sdt[(size_t)(c * BB + b) * DD + d] = sum_dt;
}

// ---------------------------------------------------------------------------
// Phase 2: combine chunk boundaries.
// ---------------------------------------------------------------------------
__global__ __launch_bounds__(256) void scan_phase2(
    const float* __restrict__ A_log,
    const float* __restrict__ Lst,
    const float* __restrict__ sdt,
    float* __restrict__ Sinit)
{
    int g = blockIdx.x * 256 + threadIdx.x;
    int n = g & 15;
    int d = (g >> 4) & (DD - 1);
    int b = g >> 14;
    float a2 = -__expf(A_log[(size_t)d * NN + n]) * L2E;
    float s = 0.f;
    for (int c = 0; c < NCH; c++) {
        size_t idx = ((size_t)(c * BB + b) * DD + d) * NN + n;
        Sinit[idx] = s;
        float P = exp2f(a2 * sdt[(size_t)(c * BB + b) * DD + d]);
        s = fmaf(P, s, Lst[idx]);
    }
}

// ---------------------------------------------------------------------------
// Phase 3: replay with correct init state; g = y*spike*silu(z) stored bf16.
// ---------------------------------------------------------------------------
__global__ __launch_bounds__(256) void scan_phase3(
    const float* __restrict__ xz,
    const float* __restrict__ dtb,
    const float* __restrict__ bc,
    const float* __restrict__ A_log,
    const float* __restrict__ Sinit,
    const float* __restrict__ D_skip,
    const float* __restrict__ v_th,
    short* __restrict__ gout)
{
    int tid = threadIdx.x;
    int d = blockIdx.x * 256 + tid;
    int b = blockIdx.y;
    int c = blockIdx.z;

    __shared__ float sB[LCH][NN];
    __shared__ float sC[LCH][NN];
    for (int i = tid; i < LCH * 32; i += 256) {
        int j = i >> 5, m = i & 31;
        int r = b * TT + c * LCH + j;
        float v = bc[(size_t)r * 32 + m];
        if (m < 16) sB[j][m] = v; else sC[j][m - 16] = v;
    }
    __syncthreads();

    float a2[NN];
    #pragma unroll
    for (int n = 0; n < NN; n++)
        a2[n] = -__expf(A_log[(size_t)d * NN + n]) * L2E;

    size_t base = ((size_t)(c * BB + b) * DD + d) * NN;
    float s[NN];
    #pragma unroll
    for (int n = 0; n < NN; n++) s[n] = Sinit[base + n];

    float dsk = D_skip[d];
    float vth = fmaxf(v_th[d], V_TH_MIN);

    for (int j = 0; j < LCH; j++) {
        int r = b * TT + c * LCH + j;
        float dt = dtb[(size_t)r * DD + d];
        float x  = xz[(size_t)r * (2 * DD) + d];
        float z  = xz[(size_t)r * (2 * DD) + DD + d];
        float dtx = dt * x;
        float y = 0.f;
        #pragma unroll
        for (int n = 0; n < NN; n++) {
            float dec = exp2f(a2[n] * dt);
            s[n] = fmaf(dec, s[n], dtx * sB[j][n]);
            y = fmaf(s[n], sC[j][n], y);
        }
        y = fmaf(dsk, x, y);
        float sp = 1.f / (1.f + __expf(-K_STEEP * (y - vth)));
        float sz = z / (1.f + __expf(-z));
        gout[(size_t)r * DD + d] = f2bf(y * sp * sz);
    }
}

// ---------------------------------------------------------------------------
extern "C" void kernel_launch(void* const* d_in, const int* in_sizes, int n_in,
                              void* d_out, int out_size, void* d_ws, size_t ws_size,
                              hipStream_t stream) {
    const float* H      = (const float*)d_in[0];   // (2,1024,1024)
    const float* W_xz   = (const float*)d_in[1];   // (1024,2048)
    const float* W_dt   = (const float*)d_in[2];   // (1024,1024)
    const float* b_dt   = (const float*)d_in[3];   // (1024,)
    const float* A_log  = (const float*)d_in[4];   // (1024,16)
    const float* W_B    = (const float*)d_in[5];   // (1024,16)
    const float* W_C    = (const float*)d_in[6];   // (1024,16)
    const float* D_skip = (const float*)d_in[7];   // (1024,)
    const float* W_out  = (const float*)d_in[8];   // (1024,1024)
    const float* v_th   = (const float*)d_in[9];   // (1024,)
    float* out = (float*)d_out;

    float* ws  = (float*)d_ws;
    float* xz  = ws;                  // 2048*2048
    float* dtb = xz + 4194304;        // 2048*1024
    float* bcb = dtb + 2097152;       // 2048*32
    float* Lst = bcb + 65536;         // 32*2*1024*16
    float* sdt = Lst + 1048576;       // 32*2*1024
    float* Sin = sdt + 65536;         // 1048576
    short* p16 = (short*)(Sin + 1048576);  // 4194304 shorts, time-shared:
    short* Hb    = p16;               //   phase A: Hb[2M] | WxzT[2M]
    short* WxzT  = p16 + 2097152;
    short* xb    = p16;               //   phase B: xb[2M] | WdtT[1M]
    short* WdtT  = p16 + 2097152;
    short* gb    = p16;               //   phase C: gb[2M] | WoutT[1M]
    short* WoutT = p16 + 2097152;

    const int M = BB * TT;  // 2048

    // converts for G1
    convert_bf16<<<2048, 256, 0, stream>>>(H, Hb);
    convert_transpose<<<dim3(2 * DD / 32, DD / 32), 256, 0, stream>>>(
        W_xz, WxzT, DD, 2 * DD);
    // 1) XZ = H @ W_xz   (fp32 out)
    gemm_mfma<0><<<dim3(2 * DD / 128, M / 128), 256, 0, stream>>>(
        Hb, WxzT, xz, 2 * DD, M, 2 * DD, DD, nullptr, nullptr);
    // converts for G2 (reuse pool: Hb, WxzT dead)
    convert_x<<<2048, 256, 0, stream>>>(xz, xb);
    convert_transpose<<<dim3(DD / 32, DD / 32), 256, 0, stream>>>(
        W_dt, WdtT, DD, DD);
    // 2) dt = softplus(x @ W_dt + b_dt)
    gemm_mfma<1><<<dim3(DD / 128, M / 128), 256, 0, stream>>>(
        xb, WdtT, dtb, DD, M, DD, DD, b_dt, nullptr);
    // 3) Bm|Cm (fp32)
    bc_kernel<<<M, 256, 0, stream>>>(H, W_B, W_C, bcb);
    // 4) chunked scan
    scan_phase1<<<dim3(DD / 256, BB, NCH), 256, 0, stream>>>(
        xz, dtb, bcb, A_log, Lst, sdt);
    scan_phase2<<<(BB * DD * NN) / 256, 256, 0, stream>>>(A_log, Lst, sdt, Sin);
    // convert for G3 (reuse pool: xb, WdtT dead)
    convert_transpose<<<dim3(DD / 32, DD / 32), 256, 0, stream>>>(
        W_out, WoutT, DD, DD);
    scan_phase3<<<dim3(DD / 256, BB, NCH), 256, 0, stream>>>(
        xz, dtb, bcb, A_log, Sin, D_skip, v_th, gb);
    // 5) out = g @ W_out - H
    gemm_mfma<2><<<dim3(DD / 128, M / 128), 256, 0, stream>>>(
        gb, WoutT, out, DD, M, DD, DD, nullptr, H);
}

// Round 3
// 178.988 us; speedup vs baseline: 2.3745x; 1.2685x over previous
//
#include <hip/hip_runtime.h>
#include <hip/hip_bf16.h>
#include <stdint.h>

// Problem constants: B=2, T=1024, D=1024, N=16
#define TT 1024
#define BB 2
#define DD 1024
#define NN 16
#define NCH 32   // chunks
#define LCH 32   // chunk length (NCH*LCH == TT)

#define K_STEEP 10.0f
#define V_TH_MIN 0.1f
#define L2E 1.44269504088896f

typedef __bf16 bf16x8 __attribute__((ext_vector_type(8)));
typedef float f32x4 __attribute__((ext_vector_type(4)));

__device__ __forceinline__ short f2bf(float f) {
    union { float f; unsigned u; } c; c.f = f;
    unsigned r = (c.u + 0x7fffu + ((c.u >> 16) & 1u)) >> 16;
    return (short)r;
}

__device__ __forceinline__ void gload_lds16(const void* g, void* l) {
    __builtin_amdgcn_global_load_lds(
        (const __attribute__((address_space(1))) void*)g,
        (__attribute__((address_space(3))) void*)l, 16, 0, 0);
}

// ---------------------------------------------------------------------------
// bf16 MFMA GEMM (m97 structure): C[M][N] = A[M][K] @ BT[N][K]^T  (+ epilogue)
// A: M x K bf16 row-major.  BT: N x K bf16 row-major (i.e. B transposed).
// 128x128 tile, BK=32, 256 threads (4 waves, 2x2), 4x4 16x16x32 frags/wave.
// EPI 0: plain fp32 store
// EPI 1: softplus(v + bias[col])
// EPI 2: v - sub[row*ldc + col]
// EPI 3: fp32 store + bf16 copy of cols < DD into xbuf[row*DD+col]
// ---------------------------------------------------------------------------
template<int EPI>
__global__ __launch_bounds__(256) void gemm_mfma(
    const short* __restrict__ A,
    const short* __restrict__ BT,
    float* __restrict__ C, int ldc,
    int M, int Ncols, int K,
    const float* __restrict__ bias,
    const float* __restrict__ sub,
    short* __restrict__ xbuf)
{
    __shared__ short As[128 * 32];   // [row][k], 64B rows
    __shared__ short Bs[128 * 32];   // [n][k]

    const int tid = threadIdx.x;
    const int wave = tid >> 6, lane = tid & 63;
    const int bm = blockIdx.y * 128, bn = blockIdx.x * 128;
    const int wr = wave >> 1, wc = wave & 1;

    f32x4 acc[4][4] = {};

    const int kk = (lane >> 4) * 8;   // k-slot for frags
    const int r16 = lane & 15;

    for (int k0 = 0; k0 < K; k0 += 32) {
        // stage A,B tiles: 8192B each, 16B per lane-issue
        #pragma unroll
        for (int it = 0; it < 2; it++) {
            int off = wave * 2048 + it * 1024 + lane * 16;  // byte offset in tile
            int row = off >> 6;             // 64B per row (32 bf16)
            int ke  = (off & 63) >> 1;      // element offset in k
            gload_lds16(A + (size_t)(bm + row) * K + k0 + ke, (char*)As + off);
            gload_lds16(BT + (size_t)(bn + row) * K + k0 + ke, (char*)Bs + off);
        }
        __syncthreads();

        bf16x8 a[4], b[4];
        #pragma unroll
        for (int i = 0; i < 4; i++)
            a[i] = *(const bf16x8*)&As[(wr * 64 + i * 16 + r16) * 32 + kk];
        #pragma unroll
        for (int j = 0; j < 4; j++)
            b[j] = *(const bf16x8*)&Bs[(wc * 64 + j * 16 + r16) * 32 + kk];
        #pragma unroll
        for (int i = 0; i < 4; i++)
            #pragma unroll
            for (int j = 0; j < 4; j++)
                acc[i][j] = __builtin_amdgcn_mfma_f32_16x16x32_bf16(
                    a[i], b[j], acc[i][j], 0, 0, 0);
        __syncthreads();
    }

    // epilogue: C/D layout col = lane&15, row = (lane>>4)*4 + reg (m89/m91)
    #pragma unroll
    for (int i = 0; i < 4; i++) {
        #pragma unroll
        for (int j = 0; j < 4; j++) {
            #pragma unroll
            for (int g = 0; g < 4; g++) {
                int row = bm + wr * 64 + i * 16 + (lane >> 4) * 4 + g;
                int col = bn + wc * 64 + j * 16 + r16;
                float v = acc[i][j][g];
                if (EPI == 1) {
                    v += bias[col];
                    v = fmaxf(v, 0.f) + log1pf(__expf(-fabsf(v)));
                }
                if (EPI == 2) {
                    v -= sub[(size_t)row * ldc + col];
                }
                C[(size_t)row * ldc + col] = v;
                if (EPI == 3 && col < DD) {
                    xbuf[(size_t)row * DD + col] = f2bf(v);
                }
            }
        }
    }
}

// ---------------------------------------------------------------------------
// bc via MFMA: bc[2048][32] = Hb[2048][1024] @ WbcT[32][1024]^T  (fp32 out)
// BM=64, BK=64, 32 blocks, 4 waves (16 rows x 32 cols each).
// ---------------------------------------------------------------------------
__global__ __launch_bounds__(256) void bc_mfma(
    const short* __restrict__ Hb,
    const short* __restrict__ WbcT,
    float* __restrict__ bc)
{
    __shared__ short As[64 * 64];   // 8KB, 128B rows
    __shared__ short Bs[32 * 64];   // 4KB

    const int tid = threadIdx.x;
    const int wave = tid >> 6, lane = tid & 63;
    const int bm = blockIdx.x * 64;
    const int kk = (lane >> 4) * 8;
    const int r16 = lane & 15;

    f32x4 acc[2] = {};

    for (int k0 = 0; k0 < DD; k0 += 64) {
        #pragma unroll
        for (int it = 0; it < 2; it++) {
            int off = it * 4096 + tid * 16;
            int row = off >> 7;
            int ke  = (off & 127) >> 1;
            gload_lds16(Hb + (size_t)(bm + row) * DD + k0 + ke, (char*)As + off);
        }
        {
            int off = tid * 16;
            int row = off >> 7;
            int ke  = (off & 127) >> 1;
            gload_lds16(WbcT + (size_t)row * DD + k0 + ke, (char*)Bs + off);
        }
        __syncthreads();

        bf16x8 alo = *(const bf16x8*)&As[(wave * 16 + r16) * 64 + kk];
        bf16x8 ahi = *(const bf16x8*)&As[(wave * 16 + r16) * 64 + kk + 32];
        #pragma unroll
        for (int j = 0; j < 2; j++) {
            bf16x8 blo = *(const bf16x8*)&Bs[(j * 16 + r16) * 64 + kk];
            bf16x8 bhi = *(const bf16x8*)&Bs[(j * 16 + r16) * 64 + kk + 32];
            acc[j] = __builtin_amdgcn_mfma_f32_16x16x32_bf16(alo, blo, acc[j], 0, 0, 0);
            acc[j] = __builtin_amdgcn_mfma_f32_16x16x32_bf16(ahi, bhi, acc[j], 0, 0, 0);
        }
        __syncthreads();
    }

    #pragma unroll
    for (int j = 0; j < 2; j++)
        #pragma unroll
        for (int g = 0; g < 4; g++) {
            int row = bm + wave * 16 + (lane >> 4) * 4 + g;
            int col = j * 16 + r16;
            bc[(size_t)row * 32 + col] = acc[j][g];
        }
}

// ---------------------------------------------------------------------------
// fp32 -> bf16 plain convert
// ---------------------------------------------------------------------------
__global__ __launch_bounds__(256) void convert_bf16(
    const float* __restrict__ in, short* __restrict__ out)
{
    int i = (blockIdx.x * 256 + threadIdx.x) * 4;
    float4 v = *(const float4*)&in[i];
    short4 o = { f2bf(v.x), f2bf(v.y), f2bf(v.z), f2bf(v.w) };
    *(short4*)&out[i] = o;
}

// ---------------------------------------------------------------------------
// fp32 W[K][N] -> bf16 WT[N][K] (transpose), 32x32 tiles
// ---------------------------------------------------------------------------
__global__ __launch_bounds__(256) void convert_transpose(
    const float* __restrict__ W, short* __restrict__ WT, int K, int N)
{
    __shared__ float t[32][33];
    int k0 = blockIdx.y * 32, n0 = blockIdx.x * 32;
    int r = threadIdx.x >> 3, q = threadIdx.x & 7;
    float4 v = *(const float4*)&W[(size_t)(k0 + r) * N + n0 + q * 4];
    t[r][q * 4 + 0] = v.x; t[r][q * 4 + 1] = v.y;
    t[r][q * 4 + 2] = v.z; t[r][q * 4 + 3] = v.w;
    __syncthreads();
    short4 o = { f2bf(t[q * 4 + 0][r]), f2bf(t[q * 4 + 1][r]),
                 f2bf(t[q * 4 + 2][r]), f2bf(t[q * 4 + 3][r]) };
    *(short4*)&WT[(size_t)(n0 + r) * K + k0 + q * 4] = o;
}

// ---------------------------------------------------------------------------
// W_B,W_C (each [1024][16] fp32) -> WbcT [32][1024] bf16
// WbcT[n][k] = W_B[k][n] (n<16) else W_C[k][n-16]
// ---------------------------------------------------------------------------
__global__ __launch_bounds__(256) void convert_bc_w(
    const float* __restrict__ W_B,
    const float* __restrict__ W_C,
    short* __restrict__ WbcT)
{
    int g = blockIdx.x * 256 + threadIdx.x;   // 0..32767
    int k = g & (DD - 1);
    int n = g >> 10;
    float v = (n < 16) ? W_B[(size_t)k * NN + n] : W_C[(size_t)k * NN + n - 16];
    WbcT[(size_t)n * DD + k] = f2bf(v);
}

// ---------------------------------------------------------------------------
// Phase 1: per (b,d,chunk) local scan with s0=0.
// ---------------------------------------------------------------------------
__global__ __launch_bounds__(256) void scan_phase1(
    const float* __restrict__ xz,
    const float* __restrict__ dtb,
    const float* __restrict__ bc,
    const float* __restrict__ A_log,
    float* __restrict__ Lst,
    float* __restrict__ sdt)
{
    int tid = threadIdx.x;
    int d = blockIdx.x * 256 + tid;
    int b = blockIdx.y;
    int c = blockIdx.z;

    __shared__ float sBm[LCH][NN];
    for (int i = tid; i < LCH * NN; i += 256) {
        int j = i >> 4, n = i & 15;
        int r = b * TT + c * LCH + j;
        sBm[j][n] = bc[(size_t)r * 32 + n];
    }
    __syncthreads();

    float a2[NN];
    #pragma unroll
    for (int n = 0; n < NN; n++)
        a2[n] = -__expf(A_log[(size_t)d * NN + n]) * L2E;

    float s[NN];
    #pragma unroll
    for (int n = 0; n < NN; n++) s[n] = 0.f;

    float sum_dt = 0.f;
    for (int j = 0; j < LCH; j++) {
        int r = b * TT + c * LCH + j;
        float dt = dtb[(size_t)r * DD + d];
        float x  = xz[(size_t)r * (2 * DD) + d];
        float dtx = dt * x;
        sum_dt += dt;
        #pragma unroll
        for (int n = 0; n < NN; n++) {
            float dec = exp2f(a2[n] * dt);
            s[n] = fmaf(dec, s[n], dtx * sBm[j][n]);
        }
    }
    size_t base = ((size_t)(c * BB + b) * DD + d) * NN;
    #pragma unroll
    for (int n = 0; n < NN; n++) Lst[base + n] = s[n];
    sdt[(size_t)(c * BB + b) * DD + d] = sum_dt;
}

// ---------------------------------------------------------------------------
// Phase 2: combine chunk boundaries.
// ---------------------------------------------------------------------------
__global__ __launch_bounds__(256) void scan_phase2(
    const float* __restrict__ A_log,
    const float* __restrict__ Lst,
    const float* __restrict__ sdt,
    float* __restrict__ Sinit)
{
    int g = blockIdx.x * 256 + threadIdx.x;
    int n = g & 15;
    int d = (g >> 4) & (DD - 1);
    int b = g >> 14;
    float a2 = -__expf(A_log[(size_t)d * NN + n]) * L2E;
    float s = 0.f;
    for (int c = 0; c < NCH; c++) {
        size_t idx = ((size_t)(c * BB + b) * DD + d) * NN + n;
        Sinit[idx] = s;
        float P = exp2f(a2 * sdt[(size_t)(c * BB + b) * DD + d]);
        s = fmaf(P, s, Lst[idx]);
    }
}

// ---------------------------------------------------------------------------
// Phase 3: replay with correct init state; g = y*spike*silu(z) stored bf16.
// ---------------------------------------------------------------------------
__global__ __launch_bounds__(256) void scan_phase3(
    const float* __restrict__ xz,
    const float* __restrict__ dtb,
    const float* __restrict__ bc,
    const float* __restrict__ A_log,
    const float* __restrict__ Sinit,
    const float* __restrict__ D_skip,
    const float* __restrict__ v_th,
    short* __restrict__ gout)
{
    int tid = threadIdx.x;
    int d = blockIdx.x * 256 + tid;
    int b = blockIdx.y;
    int c = blockIdx.z;

    __shared__ float sB[LCH][NN];
    __shared__ float sC[LCH][NN];
    for (int i = tid; i < LCH * 32; i += 256) {
        int j = i >> 5, m = i & 31;
        int r = b * TT + c * LCH + j;
        float v = bc[(size_t)r * 32 + m];
        if (m < 16) sB[j][m] = v; else sC[j][m - 16] = v;
    }
    __syncthreads();

    float a2[NN];
    #pragma unroll
    for (int n = 0; n < NN; n++)
        a2[n] = -__expf(A_log[(size_t)d * NN + n]) * L2E;

    size_t base = ((size_t)(c * BB + b) * DD + d) * NN;
    float s[NN];
    #pragma unroll
    for (int n = 0; n < NN; n++) s[n] = Sinit[base + n];

    float dsk = D_skip[d];
    float vth = fmaxf(v_th[d], V_TH_MIN);

    for (int j = 0; j < LCH; j++) {
        int r = b * TT + c * LCH + j;
        float dt = dtb[(size_t)r * DD + d];
        float x  = xz[(size_t)r * (2 * DD) + d];
        float z  = xz[(size_t)r * (2 * DD) + DD + d];
        float dtx = dt * x;
        float y = 0.f;
        #pragma unroll
        for (int n = 0; n < NN; n++) {
            float dec = exp2f(a2[n] * dt);
            s[n] = fmaf(dec, s[n], dtx * sB[j][n]);
            y = fmaf(s[n], sC[j][n], y);
        }
        y = fmaf(dsk, x, y);
        float sp = 1.f / (1.f + __expf(-K_STEEP * (y - vth)));
        float sz = z / (1.f + __expf(-z));
        gout[(size_t)r * DD + d] = f2bf(y * sp * sz);
    }
}

// ---------------------------------------------------------------------------
extern "C" void kernel_launch(void* const* d_in, const int* in_sizes, int n_in,
                              void* d_out, int out_size, void* d_ws, size_t ws_size,
                              hipStream_t stream) {
    const float* H      = (const float*)d_in[0];   // (2,1024,1024)
    const float* W_xz   = (const float*)d_in[1];   // (1024,2048)
    const float* W_dt   = (const float*)d_in[2];   // (1024,1024)
    const float* b_dt   = (const float*)d_in[3];   // (1024,)
    const float* A_log  = (const float*)d_in[4];   // (1024,16)
    const float* W_B    = (const float*)d_in[5];   // (1024,16)
    const float* W_C    = (const float*)d_in[6];   // (1024,16)
    const float* D_skip = (const float*)d_in[7];   // (1024,)
    const float* W_out  = (const float*)d_in[8];   // (1024,1024)
    const float* v_th   = (const float*)d_in[9];   // (1024,)
    float* out = (float*)d_out;

    float* ws  = (float*)d_ws;
    float* xz  = ws;                  // 2048*2048
    float* dtb = xz + 4194304;        // 2048*1024
    float* bcb = dtb + 2097152;       // 2048*32
    float* Lst = bcb + 65536;         // 32*2*1024*16
    float* sdt = Lst + 1048576;       // 32*2*1024
    float* Sin = sdt + 65536;         // 1048576
    short* p16 = (short*)(Sin + 1048576);  // 4194304 shorts, time-shared:
    short* Hb    = p16;               //   A: Hb[2M] | WxzT[2M]   (until bc/G1)
    short* WxzT  = p16 + 2097152;
    short* WdtT  = p16 + 2097152;     //   B: overwrites WxzT after G1
    short* gb    = p16;               //   C: overwrites Hb after bc
    short* WoutT = p16 + 2097152;     //      overwrites WdtT after G2
    short* xb    = (short*)Sin;       // alias: dead before phase2 writes Sin
    short* WbcT  = (short*)Lst;       // alias: dead before phase1 writes Lst

    const int M = BB * TT;  // 2048

    // converts for G1 + bc
    convert_bf16<<<2048, 256, 0, stream>>>(H, Hb);
    convert_transpose<<<dim3(2 * DD / 32, DD / 32), 256, 0, stream>>>(
        W_xz, WxzT, DD, 2 * DD);
    convert_bc_w<<<128, 256, 0, stream>>>(W_B, W_C, WbcT);
    // 1) XZ = H @ W_xz  (fp32) + bf16 x copy fused
    gemm_mfma<3><<<dim3(2 * DD / 128, M / 128), 256, 0, stream>>>(
        Hb, WxzT, xz, 2 * DD, M, 2 * DD, DD, nullptr, nullptr, xb);
    // 2) Bm|Cm via MFMA (Hb still live)
    bc_mfma<<<32, 256, 0, stream>>>(Hb, WbcT, bcb);
    // 3) dt = softplus(x @ W_dt + b_dt)
    convert_transpose<<<dim3(DD / 32, DD / 32), 256, 0, stream>>>(
        W_dt, WdtT, DD, DD);
    gemm_mfma<1><<<dim3(DD / 128, M / 128), 256, 0, stream>>>(
        xb, WdtT, dtb, DD, M, DD, DD, b_dt, nullptr, nullptr);
    // 4) chunked scan
    scan_phase1<<<dim3(DD / 256, BB, NCH), 256, 0, stream>>>(
        xz, dtb, bcb, A_log, Lst, sdt);
    scan_phase2<<<(BB * DD * NN) / 256, 256, 0, stream>>>(A_log, Lst, sdt, Sin);
    convert_transpose<<<dim3(DD / 32, DD / 32), 256, 0, stream>>>(
        W_out, WoutT, DD, DD);
    scan_phase3<<<dim3(DD / 256, BB, NCH), 256, 0, stream>>>(
        xz, dtb, bcb, A_log, Sin, D_skip, v_th, gb);
    // 5) out = g @ W_out - H
    gemm_mfma<2><<<dim3(DD / 128, M / 128), 256, 0, stream>>>(
        gb, WoutT, out, DD, M, DD, DD, nullptr, H, nullptr);
}

// Round 4
// 147.453 us; speedup vs baseline: 2.8823x; 1.2139x over previous
//
#include <hip/hip_runtime.h>
#include <hip/hip_bf16.h>
#include <stdint.h>

// Problem constants: B=2, T=1024, D=1024, N=16
#define TT 1024
#define BB 2
#define DD 1024
#define NN 16
#define NCH 32   // chunks
#define LCH 32   // chunk length (NCH*LCH == TT)

#define K_STEEP 10.0f
#define V_TH_MIN 0.1f
#define L2E 1.44269504088896f

typedef __bf16 bf16x8 __attribute__((ext_vector_type(8)));
typedef float f32x4 __attribute__((ext_vector_type(4)));

__device__ __forceinline__ short f2bf(float f) {
    union { float f; unsigned u; } c; c.f = f;
    unsigned r = (c.u + 0x7fffu + ((c.u >> 16) & 1u)) >> 16;
    return (short)r;
}

__device__ __forceinline__ void gload_lds16(const void* g, void* l) {
    __builtin_amdgcn_global_load_lds(
        (const __attribute__((address_space(1))) void*)g,
        (__attribute__((address_space(3))) void*)l, 16, 0, 0);
}

// ---------------------------------------------------------------------------
// bf16 MFMA GEMM: C[M][N] = A[M][K] @ BT[N][K]^T  (+ epilogue)
// Tile BM x 128, BK=32, 256 threads (4 waves, 2x2).
// BM=64: acc[2][4]/wave; BM=32: acc[1][4]/wave.  Grid sized for >=2 blocks/CU.
// EPI 0: plain fp32 store
// EPI 1: softplus(v + bias[col])
// EPI 2: v - sub[row*ldc + col]
// EPI 3: fp32 store + bf16 copy of cols < DD into xbuf[row*DD+col]
// ---------------------------------------------------------------------------
template<int BM, int EPI>
__global__ __launch_bounds__(256) void gemm_mfma(
    const short* __restrict__ A,
    const short* __restrict__ BT,
    float* __restrict__ C, int ldc,
    int M, int Ncols, int K,
    const float* __restrict__ bias,
    const float* __restrict__ sub,
    short* __restrict__ xbuf)
{
    constexpr int RI = BM / 32;          // row frags per wave
    __shared__ short As[BM * 32];        // [row][k], 64B rows
    __shared__ short Bs[128 * 32];       // [n][k]

    const int tid = threadIdx.x;
    const int wave = tid >> 6, lane = tid & 63;
    const int bm = blockIdx.y * BM, bn = blockIdx.x * 128;
    const int wr = wave >> 1, wc = wave & 1;

    f32x4 acc[RI][4] = {};

    const int kk = (lane >> 4) * 8;   // k-slot for frags
    const int r16 = lane & 15;

    for (int k0 = 0; k0 < K; k0 += 32) {
        // stage B tile: 8192B, 2 x 16B per thread
        #pragma unroll
        for (int it = 0; it < 2; it++) {
            int off = it * 4096 + tid * 16;
            int row = off >> 6;             // 64B per row (32 bf16)
            int ke  = (off & 63) >> 1;
            gload_lds16(BT + (size_t)(bn + row) * K + k0 + ke, (char*)Bs + off);
        }
        // stage A tile: BM*64 bytes (whole waves participate)
        if (tid < BM * 4) {
            int off = tid * 16;
            int row = off >> 6;
            int ke  = (off & 63) >> 1;
            gload_lds16(A + (size_t)(bm + row) * K + k0 + ke, (char*)As + off);
        }
        __syncthreads();

        bf16x8 a[RI], b[4];
        #pragma unroll
        for (int i = 0; i < RI; i++)
            a[i] = *(const bf16x8*)&As[(wr * (BM / 2) + i * 16 + r16) * 32 + kk];
        #pragma unroll
        for (int j = 0; j < 4; j++)
            b[j] = *(const bf16x8*)&Bs[(wc * 64 + j * 16 + r16) * 32 + kk];
        #pragma unroll
        for (int i = 0; i < RI; i++)
            #pragma unroll
            for (int j = 0; j < 4; j++)
                acc[i][j] = __builtin_amdgcn_mfma_f32_16x16x32_bf16(
                    a[i], b[j], acc[i][j], 0, 0, 0);
        __syncthreads();
    }

    // epilogue: C/D layout col = lane&15, row = (lane>>4)*4 + reg (m89/m91)
    #pragma unroll
    for (int i = 0; i < RI; i++) {
        #pragma unroll
        for (int j = 0; j < 4; j++) {
            #pragma unroll
            for (int g = 0; g < 4; g++) {
                int row = bm + wr * (BM / 2) + i * 16 + (lane >> 4) * 4 + g;
                int col = bn + wc * 64 + j * 16 + r16;
                float v = acc[i][j][g];
                if (EPI == 1) {
                    v += bias[col];
                    v = fmaxf(v, 0.f) + log1pf(__expf(-fabsf(v)));
                }
                if (EPI == 2) {
                    v -= sub[(size_t)row * ldc + col];
                }
                C[(size_t)row * ldc + col] = v;
                if (EPI == 3 && col < DD) {
                    xbuf[(size_t)row * DD + col] = f2bf(v);
                }
            }
        }
    }
}

// ---------------------------------------------------------------------------
// bc via MFMA: bc[2048][32] = Hb[2048][1024] @ WbcT[32][1024]^T  (fp32 out)
// BM=64, BK=64, 32 blocks, 4 waves (16 rows x 32 cols each).
// ---------------------------------------------------------------------------
__global__ __launch_bounds__(256) void bc_mfma(
    const short* __restrict__ Hb,
    const short* __restrict__ WbcT,
    float* __restrict__ bc)
{
    __shared__ short As[64 * 64];   // 8KB, 128B rows
    __shared__ short Bs[32 * 64];   // 4KB

    const int tid = threadIdx.x;
    const int wave = tid >> 6, lane = tid & 63;
    const int bm = blockIdx.x * 64;
    const int kk = (lane >> 4) * 8;
    const int r16 = lane & 15;

    f32x4 acc[2] = {};

    for (int k0 = 0; k0 < DD; k0 += 64) {
        #pragma unroll
        for (int it = 0; it < 2; it++) {
            int off = it * 4096 + tid * 16;
            int row = off >> 7;
            int ke  = (off & 127) >> 1;
            gload_lds16(Hb + (size_t)(bm + row) * DD + k0 + ke, (char*)As + off);
        }
        {
            int off = tid * 16;
            int row = off >> 7;
            int ke  = (off & 127) >> 1;
            gload_lds16(WbcT + (size_t)row * DD + k0 + ke, (char*)Bs + off);
        }
        __syncthreads();

        bf16x8 alo = *(const bf16x8*)&As[(wave * 16 + r16) * 64 + kk];
        bf16x8 ahi = *(const bf16x8*)&As[(wave * 16 + r16) * 64 + kk + 32];
        #pragma unroll
        for (int j = 0; j < 2; j++) {
            bf16x8 blo = *(const bf16x8*)&Bs[(j * 16 + r16) * 64 + kk];
            bf16x8 bhi = *(const bf16x8*)&Bs[(j * 16 + r16) * 64 + kk + 32];
            acc[j] = __builtin_amdgcn_mfma_f32_16x16x32_bf16(alo, blo, acc[j], 0, 0, 0);
            acc[j] = __builtin_amdgcn_mfma_f32_16x16x32_bf16(ahi, bhi, acc[j], 0, 0, 0);
        }
        __syncthreads();
    }

    #pragma unroll
    for (int j = 0; j < 2; j++)
        #pragma unroll
        for (int g = 0; g < 4; g++) {
            int row = bm + wave * 16 + (lane >> 4) * 4 + g;
            int col = j * 16 + r16;
            bc[(size_t)row * 32 + col] = acc[j][g];
        }
}

// ---------------------------------------------------------------------------
// fp32 -> bf16 plain convert
// ---------------------------------------------------------------------------
__global__ __launch_bounds__(256) void convert_bf16(
    const float* __restrict__ in, short* __restrict__ out)
{
    int i = (blockIdx.x * 256 + threadIdx.x) * 4;
    float4 v = *(const float4*)&in[i];
    short4 o = { f2bf(v.x), f2bf(v.y), f2bf(v.z), f2bf(v.w) };
    *(short4*)&out[i] = o;
}

// ---------------------------------------------------------------------------
// fp32 W[K][N] -> bf16 WT[N][K] (transpose), 32x32 tiles
// ---------------------------------------------------------------------------
__global__ __launch_bounds__(256) void convert_transpose(
    const float* __restrict__ W, short* __restrict__ WT, int K, int N)
{
    __shared__ float t[32][33];
    int k0 = blockIdx.y * 32, n0 = blockIdx.x * 32;
    int r = threadIdx.x >> 3, q = threadIdx.x & 7;
    float4 v = *(const float4*)&W[(size_t)(k0 + r) * N + n0 + q * 4];
    t[r][q * 4 + 0] = v.x; t[r][q * 4 + 1] = v.y;
    t[r][q * 4 + 2] = v.z; t[r][q * 4 + 3] = v.w;
    __syncthreads();
    short4 o = { f2bf(t[q * 4 + 0][r]), f2bf(t[q * 4 + 1][r]),
                 f2bf(t[q * 4 + 2][r]), f2bf(t[q * 4 + 3][r]) };
    *(short4*)&WT[(size_t)(n0 + r) * K + k0 + q * 4] = o;
}

// ---------------------------------------------------------------------------
// W_B,W_C (each [1024][16] fp32) -> WbcT [32][1024] bf16
// ---------------------------------------------------------------------------
__global__ __launch_bounds__(256) void convert_bc_w(
    const float* __restrict__ W_B,
    const float* __restrict__ W_C,
    short* __restrict__ WbcT)
{
    int g = blockIdx.x * 256 + threadIdx.x;   // 0..32767
    int k = g & (DD - 1);
    int n = g >> 10;
    float v = (n < 16) ? W_B[(size_t)k * NN + n] : W_C[(size_t)k * NN + n - 16];
    WbcT[(size_t)n * DD + k] = f2bf(v);
}

// ---------------------------------------------------------------------------
// Phase 1: per (b,d,chunk) local scan with s0=0.
// ---------------------------------------------------------------------------
__global__ __launch_bounds__(256) void scan_phase1(
    const float* __restrict__ xz,
    const float* __restrict__ dtb,
    const float* __restrict__ bc,
    const float* __restrict__ A_log,
    float* __restrict__ Lst,
    float* __restrict__ sdt)
{
    int tid = threadIdx.x;
    int d = blockIdx.x * 256 + tid;
    int b = blockIdx.y;
    int c = blockIdx.z;

    __shared__ float sBm[LCH][NN];
    for (int i = tid; i < LCH * NN; i += 256) {
        int j = i >> 4, n = i & 15;
        int r = b * TT + c * LCH + j;
        sBm[j][n] = bc[(size_t)r * 32 + n];
    }
    __syncthreads();

    float a2[NN];
    #pragma unroll
    for (int n = 0; n < NN; n++)
        a2[n] = -__expf(A_log[(size_t)d * NN + n]) * L2E;

    float s[NN];
    #pragma unroll
    for (int n = 0; n < NN; n++) s[n] = 0.f;

    float sum_dt = 0.f;
    for (int j = 0; j < LCH; j++) {
        int r = b * TT + c * LCH + j;
        float dt = dtb[(size_t)r * DD + d];
        float x  = xz[(size_t)r * (2 * DD) + d];
        float dtx = dt * x;
        sum_dt += dt;
        #pragma unroll
        for (int n = 0; n < NN; n++) {
            float dec = exp2f(a2[n] * dt);
            s[n] = fmaf(dec, s[n], dtx * sBm[j][n]);
        }
    }
    size_t base = ((size_t)(c * BB + b) * DD + d) * NN;
    #pragma unroll
    for (int n = 0; n < NN; n++) Lst[base + n] = s[n];
    sdt[(size_t)(c * BB + b) * DD + d] = sum_dt;
}

// ---------------------------------------------------------------------------
// Phase 2: combine chunk boundaries.
// ---------------------------------------------------------------------------
__global__ __launch_bounds__(256) void scan_phase2(
    const float* __restrict__ A_log,
    const float* __restrict__ Lst,
    const float* __restrict__ sdt,
    float* __restrict__ Sinit)
{
    int g = blockIdx.x * 256 + threadIdx.x;
    int n = g & 15;
    int d = (g >> 4) & (DD - 1);
    int b = g >> 14;
    float a2 = -__expf(A_log[(size_t)d * NN + n]) * L2E;
    float s = 0.f;
    for (int c = 0; c < NCH; c++) {
        size_t idx = ((size_t)(c * BB + b) * DD + d) * NN + n;
        Sinit[idx] = s;
        float P = exp2f(a2 * sdt[(size_t)(c * BB + b) * DD + d]);
        s = fmaf(P, s, Lst[idx]);
    }
}

// ---------------------------------------------------------------------------
// Phase 3: replay with correct init state; g = y*spike*silu(z) stored bf16.
// ---------------------------------------------------------------------------
__global__ __launch_bounds__(256) void scan_phase3(
    const float* __restrict__ xz,
    const float* __restrict__ dtb,
    const float* __restrict__ bc,
    const float* __restrict__ A_log,
    const float* __restrict__ Sinit,
    const float* __restrict__ D_skip,
    const float* __restrict__ v_th,
    short* __restrict__ gout)
{
    int tid = threadIdx.x;
    int d = blockIdx.x * 256 + tid;
    int b = blockIdx.y;
    int c = blockIdx.z;

    __shared__ float sB[LCH][NN];
    __shared__ float sC[LCH][NN];
    for (int i = tid; i < LCH * 32; i += 256) {
        int j = i >> 5, m = i & 31;
        int r = b * TT + c * LCH + j;
        float v = bc[(size_t)r * 32 + m];
        if (m < 16) sB[j][m] = v; else sC[j][m - 16] = v;
    }
    __syncthreads();

    float a2[NN];
    #pragma unroll
    for (int n = 0; n < NN; n++)
        a2[n] = -__expf(A_log[(size_t)d * NN + n]) * L2E;

    size_t base = ((size_t)(c * BB + b) * DD + d) * NN;
    float s[NN];
    #pragma unroll
    for (int n = 0; n < NN; n++) s[n] = Sinit[base + n];

    float dsk = D_skip[d];
    float vth = fmaxf(v_th[d], V_TH_MIN);

    for (int j = 0; j < LCH; j++) {
        int r = b * TT + c * LCH + j;
        float dt = dtb[(size_t)r * DD + d];
        float x  = xz[(size_t)r * (2 * DD) + d];
        float z  = xz[(size_t)r * (2 * DD) + DD + d];
        float dtx = dt * x;
        float y = 0.f;
        #pragma unroll
        for (int n = 0; n < NN; n++) {
            float dec = exp2f(a2[n] * dt);
            s[n] = fmaf(dec, s[n], dtx * sB[j][n]);
            y = fmaf(s[n], sC[j][n], y);
        }
        y = fmaf(dsk, x, y);
        float sp = 1.f / (1.f + __expf(-K_STEEP * (y - vth)));
        float sz = z / (1.f + __expf(-z));
        gout[(size_t)r * DD + d] = f2bf(y * sp * sz);
    }
}

// ---------------------------------------------------------------------------
extern "C" void kernel_launch(void* const* d_in, const int* in_sizes, int n_in,
                              void* d_out, int out_size, void* d_ws, size_t ws_size,
                              hipStream_t stream) {
    const float* H      = (const float*)d_in[0];   // (2,1024,1024)
    const float* W_xz   = (const float*)d_in[1];   // (1024,2048)
    const float* W_dt   = (const float*)d_in[2];   // (1024,1024)
    const float* b_dt   = (const float*)d_in[3];   // (1024,)
    const float* A_log  = (const float*)d_in[4];   // (1024,16)
    const float* W_B    = (const float*)d_in[5];   // (1024,16)
    const float* W_C    = (const float*)d_in[6];   // (1024,16)
    const float* D_skip = (const float*)d_in[7];   // (1024,)
    const float* W_out  = (const float*)d_in[8];   // (1024,1024)
    const float* v_th   = (const float*)d_in[9];   // (1024,)
    float* out = (float*)d_out;

    float* ws  = (float*)d_ws;
    float* xz  = ws;                  // 2048*2048
    float* dtb = xz + 4194304;        // 2048*1024
    float* bcb = dtb + 2097152;       // 2048*32
    float* Lst = bcb + 65536;         // 32*2*1024*16
    float* sdt = Lst + 1048576;       // 32*2*1024
    float* Sin = sdt + 65536;         // 1048576
    short* p16 = (short*)(Sin + 1048576);  // 4194304 shorts, time-shared:
    short* Hb    = p16;               //   A: Hb[2M] | WxzT[2M]   (until bc/G1)
    short* WxzT  = p16 + 2097152;
    short* WdtT  = p16 + 2097152;     //   B: overwrites WxzT after G1
    short* gb    = p16;               //   C: overwrites Hb after bc
    short* WoutT = p16 + 2097152;     //      overwrites WdtT after G2
    short* xb    = (short*)Sin;       // alias: dead before phase2 writes Sin
    short* WbcT  = (short*)Lst;       // alias: dead before phase1 writes Lst

    const int M = BB * TT;  // 2048

    // converts for G1 + bc
    convert_bf16<<<2048, 256, 0, stream>>>(H, Hb);
    convert_transpose<<<dim3(2 * DD / 32, DD / 32), 256, 0, stream>>>(
        W_xz, WxzT, DD, 2 * DD);
    convert_bc_w<<<128, 256, 0, stream>>>(W_B, W_C, WbcT);
    // 1) XZ = H @ W_xz  (fp32) + bf16 x copy fused.  512 blocks.
    gemm_mfma<64, 3><<<dim3(2 * DD / 128, M / 64), 256, 0, stream>>>(
        Hb, WxzT, xz, 2 * DD, M, 2 * DD, DD, nullptr, nullptr, xb);
    // 2) Bm|Cm via MFMA (Hb still live)
    bc_mfma<<<32, 256, 0, stream>>>(Hb, WbcT, bcb);
    // 3) dt = softplus(x @ W_dt + b_dt).  512 blocks.
    convert_transpose<<<dim3(DD / 32, DD / 32), 256, 0, stream>>>(
        W_dt, WdtT, DD, DD);
    gemm_mfma<32, 1><<<dim3(DD / 128, M / 32), 256, 0, stream>>>(
        xb, WdtT, dtb, DD, M, DD, DD, b_dt, nullptr, nullptr);
    // 4) chunked scan
    scan_phase1<<<dim3(DD / 256, BB, NCH), 256, 0, stream>>>(
        xz, dtb, bcb, A_log, Lst, sdt);
    scan_phase2<<<(BB * DD * NN) / 256, 256, 0, stream>>>(A_log, Lst, sdt, Sin);
    convert_transpose<<<dim3(DD / 32, DD / 32), 256, 0, stream>>>(
        W_out, WoutT, DD, DD);
    scan_phase3<<<dim3(DD / 256, BB, NCH), 256, 0, stream>>>(
        xz, dtb, bcb, A_log, Sin, D_skip, v_th, gb);
    // 5) out = g @ W_out - H.  512 blocks.
    gemm_mfma<32, 2><<<dim3(DD / 128, M / 32), 256, 0, stream>>>(
        gb, WoutT, out, DD, M, DD, DD, nullptr, H, nullptr);
}

// Round 5
// 126.666 us; speedup vs baseline: 3.3553x; 1.1641x over previous
//
#include <hip/hip_runtime.h>
#include <hip/hip_bf16.h>
#include <stdint.h>

// Problem constants: B=2, T=1024, D=1024, N=16
#define TT 1024
#define BB 2
#define DD 1024
#define NN 16
#define NCH 64   // chunks
#define LCH 16   // chunk length (NCH*LCH == TT)

#define K_STEEP 10.0f
#define V_TH_MIN 0.1f
#define L2E 1.44269504088896f

typedef __bf16 bf16x8 __attribute__((ext_vector_type(8)));
typedef float f32x4 __attribute__((ext_vector_type(4)));

__device__ __forceinline__ short f2bf(float f) {
    union { float f; unsigned u; } c; c.f = f;
    unsigned r = (c.u + 0x7fffu + ((c.u >> 16) & 1u)) >> 16;
    return (short)r;
}

__device__ __forceinline__ void gload_lds16(const void* g, void* l) {
    __builtin_amdgcn_global_load_lds(
        (const __attribute__((address_space(1))) void*)g,
        (__attribute__((address_space(3))) void*)l, 16, 0, 0);
}

// ---------------------------------------------------------------------------
// bf16 MFMA GEMM: C[M][N] = A[M][K] @ BT[N][K]^T  (+ epilogue)
// Tile BM x 128, BK=32, 256 threads (4 waves, 2x2).
// EPI 0: plain fp32 store
// EPI 1: softplus(v + bias[col])
// EPI 2: v - sub[row*ldc + col]
// EPI 3: fp32 store + bf16 copy of cols < DD into xbuf[row*DD+col]
// FUSE_BC: blocks with blockIdx.x == gridDim.x-1 instead compute
//   bcout[32 rows][32] = A[by*32 .. +32][K] @ WbcT[32][K]^T   (BK=64)
// ---------------------------------------------------------------------------
template<int BM, int EPI, bool FUSE_BC>
__global__ __launch_bounds__(256) void gemm_mfma(
    const short* __restrict__ A,
    const short* __restrict__ BT,
    float* __restrict__ C, int ldc,
    int M, int Ncols, int K,
    const float* __restrict__ bias,
    const float* __restrict__ sub,
    short* __restrict__ xbuf,
    const short* __restrict__ WbcT,
    float* __restrict__ bcout)
{
    constexpr int RI = BM / 32;          // row frags per wave
    constexpr int AS_SZ = (FUSE_BC && BM * 32 < 2048) ? 2048 : BM * 32;
    __shared__ short As[AS_SZ];          // GEMM: [row][32k]; bc: [32row][64k]
    __shared__ short Bs[128 * 32];       // GEMM: [n][32k]; bc: [32n][64k]

    const int tid = threadIdx.x;
    const int wave = tid >> 6, lane = tid & 63;
    const int kk = (lane >> 4) * 8;
    const int r16 = lane & 15;
    const int wr = wave >> 1, wc = wave & 1;

    if (FUSE_BC && blockIdx.x == gridDim.x - 1) {
        // ---- bc path: 32 rows x 32 cols, BK=64 ----
        const int bm2 = blockIdx.y * 32;
        f32x4 acc2 = {};
        for (int k0 = 0; k0 < K; k0 += 64) {
            int off = tid * 16;
            int row = off >> 7;            // 128B per row (64 bf16)
            int ke  = (off & 127) >> 1;
            gload_lds16(A + (size_t)(bm2 + row) * K + k0 + ke, (char*)As + off);
            gload_lds16(WbcT + (size_t)row * K + k0 + ke, (char*)Bs + off);
            __syncthreads();
            bf16x8 alo = *(const bf16x8*)&As[(wr * 16 + r16) * 64 + kk];
            bf16x8 ahi = *(const bf16x8*)&As[(wr * 16 + r16) * 64 + kk + 32];
            bf16x8 blo = *(const bf16x8*)&Bs[(wc * 16 + r16) * 64 + kk];
            bf16x8 bhi = *(const bf16x8*)&Bs[(wc * 16 + r16) * 64 + kk + 32];
            acc2 = __builtin_amdgcn_mfma_f32_16x16x32_bf16(alo, blo, acc2, 0, 0, 0);
            acc2 = __builtin_amdgcn_mfma_f32_16x16x32_bf16(ahi, bhi, acc2, 0, 0, 0);
            __syncthreads();
        }
        #pragma unroll
        for (int g = 0; g < 4; g++) {
            int row = bm2 + wr * 16 + (lane >> 4) * 4 + g;
            int col = wc * 16 + r16;
            bcout[(size_t)row * 32 + col] = acc2[g];
        }
        return;
    }

    const int bm = blockIdx.y * BM, bn = blockIdx.x * 128;
    f32x4 acc[RI][4] = {};

    for (int k0 = 0; k0 < K; k0 += 32) {
        // stage B tile: 8192B, 2 x 16B per thread
        #pragma unroll
        for (int it = 0; it < 2; it++) {
            int off = it * 4096 + tid * 16;
            int row = off >> 6;             // 64B per row (32 bf16)
            int ke  = (off & 63) >> 1;
            gload_lds16(BT + (size_t)(bn + row) * K + k0 + ke, (char*)Bs + off);
        }
        // stage A tile: BM*64 bytes
        if (tid < BM * 4) {
            int off = tid * 16;
            int row = off >> 6;
            int ke  = (off & 63) >> 1;
            gload_lds16(A + (size_t)(bm + row) * K + k0 + ke, (char*)As + off);
        }
        __syncthreads();

        bf16x8 a[RI], b[4];
        #pragma unroll
        for (int i = 0; i < RI; i++)
            a[i] = *(const bf16x8*)&As[(wr * (BM / 2) + i * 16 + r16) * 32 + kk];
        #pragma unroll
        for (int j = 0; j < 4; j++)
            b[j] = *(const bf16x8*)&Bs[(wc * 64 + j * 16 + r16) * 32 + kk];
        #pragma unroll
        for (int i = 0; i < RI; i++)
            #pragma unroll
            for (int j = 0; j < 4; j++)
                acc[i][j] = __builtin_amdgcn_mfma_f32_16x16x32_bf16(
                    a[i], b[j], acc[i][j], 0, 0, 0);
        __syncthreads();
    }

    // epilogue: C/D layout col = lane&15, row = (lane>>4)*4 + reg (m89/m91)
    #pragma unroll
    for (int i = 0; i < RI; i++) {
        #pragma unroll
        for (int j = 0; j < 4; j++) {
            #pragma unroll
            for (int g = 0; g < 4; g++) {
                int row = bm + wr * (BM / 2) + i * 16 + (lane >> 4) * 4 + g;
                int col = bn + wc * 64 + j * 16 + r16;
                float v = acc[i][j][g];
                if (EPI == 1) {
                    v += bias[col];
                    v = fmaxf(v, 0.f) + log1pf(__expf(-fabsf(v)));
                }
                if (EPI == 2) {
                    v -= sub[(size_t)row * ldc + col];
                }
                C[(size_t)row * ldc + col] = v;
                if (EPI == 3 && col < DD) {
                    xbuf[(size_t)row * DD + col] = f2bf(v);
                }
            }
        }
    }
}

// ---------------------------------------------------------------------------
// 32x32 fp32->bf16 transpose tile (shared helper for prep kernel)
// ---------------------------------------------------------------------------
__device__ __forceinline__ void tr_tile(
    const float* __restrict__ W, short* __restrict__ WT,
    int K, int N, int k0, int n0, int tid)
{
    __shared__ float t[32][33];
    int r = tid >> 3, q = tid & 7;
    float4 v = *(const float4*)&W[(size_t)(k0 + r) * N + n0 + q * 4];
    t[r][q * 4 + 0] = v.x; t[r][q * 4 + 1] = v.y;
    t[r][q * 4 + 2] = v.z; t[r][q * 4 + 3] = v.w;
    __syncthreads();
    short4 o = { f2bf(t[q * 4 + 0][r]), f2bf(t[q * 4 + 1][r]),
                 f2bf(t[q * 4 + 2][r]), f2bf(t[q * 4 + 3][r]) };
    *(short4*)&WT[(size_t)(n0 + r) * K + k0 + q * 4] = o;
}

// ---------------------------------------------------------------------------
// One-shot prep: all fp32->bf16 converts/transposes in a single launch.
// blocks [0,2048): H->Hb        [2048,4096): W_xz^T   [4096,5120): W_dt^T
// [5120,6144): W_out^T          [6144,6272): W_B|W_C pack
// ---------------------------------------------------------------------------
__global__ __launch_bounds__(256) void prep_all(
    const float* __restrict__ H,    short* __restrict__ Hb,
    const float* __restrict__ W_xz, short* __restrict__ WxzT,
    const float* __restrict__ W_dt, short* __restrict__ WdtT,
    const float* __restrict__ W_out,short* __restrict__ WoutT,
    const float* __restrict__ W_B,  const float* __restrict__ W_C,
    short* __restrict__ WbcT)
{
    int bid = blockIdx.x, tid = threadIdx.x;
    if (bid < 2048) {
        int i = bid * 1024 + tid * 4;
        float4 v = *(const float4*)&H[i];
        short4 o = { f2bf(v.x), f2bf(v.y), f2bf(v.z), f2bf(v.w) };
        *(short4*)&Hb[i] = o;
    } else if (bid < 4096) {
        int t = bid - 2048;                       // 64 n-tiles x 32 k-tiles
        tr_tile(W_xz, WxzT, DD, 2 * DD, (t >> 6) * 32, (t & 63) * 32, tid);
    } else if (bid < 5120) {
        int t = bid - 4096;
        tr_tile(W_dt, WdtT, DD, DD, (t >> 5) * 32, (t & 31) * 32, tid);
    } else if (bid < 6144) {
        int t = bid - 5120;
        tr_tile(W_out, WoutT, DD, DD, (t >> 5) * 32, (t & 31) * 32, tid);
    } else {
        int g = (bid - 6144) * 256 + tid;         // 0..32767
        int k = g & (DD - 1);
        int n = g >> 10;
        float v = (n < 16) ? W_B[(size_t)k * NN + n]
                           : W_C[(size_t)k * NN + n - 16];
        WbcT[(size_t)n * DD + k] = f2bf(v);
    }
}

// ---------------------------------------------------------------------------
// Phase 1: per (b,d,chunk) local scan with s0=0.
// ---------------------------------------------------------------------------
__global__ __launch_bounds__(256) void scan_phase1(
    const float* __restrict__ xz,
    const float* __restrict__ dtb,
    const float* __restrict__ bc,
    const float* __restrict__ A_log,
    float* __restrict__ Lst,
    float* __restrict__ sdt)
{
    int tid = threadIdx.x;
    int d = blockIdx.x * 256 + tid;
    int b = blockIdx.y;
    int c = blockIdx.z;

    __shared__ float sBm[LCH][NN];
    for (int i = tid; i < LCH * NN; i += 256) {
        int j = i >> 4, n = i & 15;
        int r = b * TT + c * LCH + j;
        sBm[j][n] = bc[(size_t)r * 32 + n];
    }
    __syncthreads();

    float a2[NN];
    #pragma unroll
    for (int n = 0; n < NN; n++)
        a2[n] = -__expf(A_log[(size_t)d * NN + n]) * L2E;

    float s[NN];
    #pragma unroll
    for (int n = 0; n < NN; n++) s[n] = 0.f;

    float sum_dt = 0.f;
    for (int j = 0; j < LCH; j++) {
        int r = b * TT + c * LCH + j;
        float dt = dtb[(size_t)r * DD + d];
        float x  = xz[(size_t)r * (2 * DD) + d];
        float dtx = dt * x;
        sum_dt += dt;
        #pragma unroll
        for (int n = 0; n < NN; n++) {
            float dec = exp2f(a2[n] * dt);
            s[n] = fmaf(dec, s[n], dtx * sBm[j][n]);
        }
    }
    size_t base = ((size_t)(c * BB + b) * DD + d) * NN;
    #pragma unroll
    for (int n = 0; n < NN; n++) Lst[base + n] = s[n];
    sdt[(size_t)(c * BB + b) * DD + d] = sum_dt;
}

// ---------------------------------------------------------------------------
// Phase 2: combine chunk boundaries.
// ---------------------------------------------------------------------------
__global__ __launch_bounds__(256) void scan_phase2(
    const float* __restrict__ A_log,
    const float* __restrict__ Lst,
    const float* __restrict__ sdt,
    float* __restrict__ Sinit)
{
    int g = blockIdx.x * 256 + threadIdx.x;
    int n = g & 15;
    int d = (g >> 4) & (DD - 1);
    int b = g >> 14;
    float a2 = -__expf(A_log[(size_t)d * NN + n]) * L2E;
    float s = 0.f;
    for (int c = 0; c < NCH; c++) {
        size_t idx = ((size_t)(c * BB + b) * DD + d) * NN + n;
        Sinit[idx] = s;
        float P = exp2f(a2 * sdt[(size_t)(c * BB + b) * DD + d]);
        s = fmaf(P, s, Lst[idx]);
    }
}

// ---------------------------------------------------------------------------
// Phase 3: replay with correct init state; g = y*spike*silu(z) stored bf16.
// ---------------------------------------------------------------------------
__global__ __launch_bounds__(256) void scan_phase3(
    const float* __restrict__ xz,
    const float* __restrict__ dtb,
    const float* __restrict__ bc,
    const float* __restrict__ A_log,
    const float* __restrict__ Sinit,
    const float* __restrict__ D_skip,
    const float* __restrict__ v_th,
    short* __restrict__ gout)
{
    int tid = threadIdx.x;
    int d = blockIdx.x * 256 + tid;
    int b = blockIdx.y;
    int c = blockIdx.z;

    __shared__ float sB[LCH][NN];
    __shared__ float sC[LCH][NN];
    for (int i = tid; i < LCH * 32; i += 256) {
        int j = i >> 5, m = i & 31;
        int r = b * TT + c * LCH + j;
        float v = bc[(size_t)r * 32 + m];
        if (m < 16) sB[j][m] = v; else sC[j][m - 16] = v;
    }
    __syncthreads();

    float a2[NN];
    #pragma unroll
    for (int n = 0; n < NN; n++)
        a2[n] = -__expf(A_log[(size_t)d * NN + n]) * L2E;

    size_t base = ((size_t)(c * BB + b) * DD + d) * NN;
    float s[NN];
    #pragma unroll
    for (int n = 0; n < NN; n++) s[n] = Sinit[base + n];

    float dsk = D_skip[d];
    float vth = fmaxf(v_th[d], V_TH_MIN);

    for (int j = 0; j < LCH; j++) {
        int r = b * TT + c * LCH + j;
        float dt = dtb[(size_t)r * DD + d];
        float x  = xz[(size_t)r * (2 * DD) + d];
        float z  = xz[(size_t)r * (2 * DD) + DD + d];
        float dtx = dt * x;
        float y = 0.f;
        #pragma unroll
        for (int n = 0; n < NN; n++) {
            float dec = exp2f(a2[n] * dt);
            s[n] = fmaf(dec, s[n], dtx * sB[j][n]);
            y = fmaf(s[n], sC[j][n], y);
        }
        y = fmaf(dsk, x, y);
        float sp = 1.f / (1.f + __expf(-K_STEEP * (y - vth)));
        float sz = z / (1.f + __expf(-z));
        gout[(size_t)r * DD + d] = f2bf(y * sp * sz);
    }
}

// ---------------------------------------------------------------------------
extern "C" void kernel_launch(void* const* d_in, const int* in_sizes, int n_in,
                              void* d_out, int out_size, void* d_ws, size_t ws_size,
                              hipStream_t stream) {
    const float* H      = (const float*)d_in[0];   // (2,1024,1024)
    const float* W_xz   = (const float*)d_in[1];   // (1024,2048)
    const float* W_dt   = (const float*)d_in[2];   // (1024,1024)
    const float* b_dt   = (const float*)d_in[3];   // (1024,)
    const float* A_log  = (const float*)d_in[4];   // (1024,16)
    const float* W_B    = (const float*)d_in[5];   // (1024,16)
    const float* W_C    = (const float*)d_in[6];   // (1024,16)
    const float* D_skip = (const float*)d_in[7];   // (1024,)
    const float* W_out  = (const float*)d_in[8];   // (1024,1024)
    const float* v_th   = (const float*)d_in[9];   // (1024,)
    float* out = (float*)d_out;

    // flat ws layout (~63 MB of 268 MB) — no aliasing
    float* ws  = (float*)d_ws;
    float* xz  = ws;                   // 4194304
    float* dtb = xz  + 4194304;        // 2097152
    float* bcb = dtb + 2097152;        // 65536
    float* Lst = bcb + 65536;          // NCH*BB*DD*NN = 2097152
    float* sdt = Lst + 2097152;        // NCH*BB*DD    = 131072
    float* Sin = sdt + 131072;         // 2097152
    short* p16   = (short*)(Sin + 2097152);
    short* Hb    = p16;                // 2097152
    short* WxzT  = Hb    + 2097152;    // 2097152
    short* WdtT  = WxzT  + 2097152;    // 1048576
    short* WoutT = WdtT  + 1048576;    // 1048576
    short* WbcT  = WoutT + 1048576;    // 32768
    short* xb    = WbcT  + 32768;      // 2097152
    short* gb    = xb    + 2097152;    // 2097152

    const int M = BB * TT;  // 2048

    // 0) all converts in one launch
    prep_all<<<6272, 256, 0, stream>>>(
        H, Hb, W_xz, WxzT, W_dt, WdtT, W_out, WoutT, W_B, W_C, WbcT);
    // 1) XZ = H @ W_xz (+ bf16 x copy) with bc fused as extra grid column
    gemm_mfma<32, 3, true><<<dim3(17, M / 32), 256, 0, stream>>>(
        Hb, WxzT, xz, 2 * DD, M, 2 * DD, DD, nullptr, nullptr, xb, WbcT, bcb);
    // 2) dt = softplus(x @ W_dt + b_dt)
    gemm_mfma<32, 1, false><<<dim3(8, M / 32), 256, 0, stream>>>(
        xb, WdtT, dtb, DD, M, DD, DD, b_dt, nullptr, nullptr, nullptr, nullptr);
    // 3) chunked scan
    scan_phase1<<<dim3(DD / 256, BB, NCH), 256, 0, stream>>>(
        xz, dtb, bcb, A_log, Lst, sdt);
    scan_phase2<<<(BB * DD * NN) / 256, 256, 0, stream>>>(A_log, Lst, sdt, Sin);
    scan_phase3<<<dim3(DD / 256, BB, NCH), 256, 0, stream>>>(
        xz, dtb, bcb, A_log, Sin, D_skip, v_th, gb);
    // 4) out = g @ W_out - H
    gemm_mfma<32, 2, false><<<dim3(8, M / 32), 256, 0, stream>>>(
        gb, WoutT, out, DD, M, DD, DD, nullptr, H, nullptr, nullptr, nullptr);
}

// Round 6
// 118.437 us; speedup vs baseline: 3.5884x; 1.0695x over previous
//
#include <hip/hip_runtime.h>
#include <hip/hip_bf16.h>
#include <stdint.h>

// Problem constants: B=2, T=1024, D=1024, N=16
#define TT 1024
#define BB 2
#define DD 1024
#define NN 16
#define NCH 64   // chunks
#define LCH 16   // chunk length (NCH*LCH == TT)

#define K_STEEP 10.0f
#define V_TH_MIN 0.1f
#define L2E 1.44269504088896f

typedef __bf16 bf16x8 __attribute__((ext_vector_type(8)));
typedef float f32x4 __attribute__((ext_vector_type(4)));

__device__ __forceinline__ short f2bf(float f) {
    union { float f; unsigned u; } c; c.f = f;
    unsigned r = (c.u + 0x7fffu + ((c.u >> 16) & 1u)) >> 16;
    return (short)r;
}
__device__ __forceinline__ float bf2f(short s) {
    union { unsigned u; float f; } c;
    c.u = ((unsigned)(unsigned short)s) << 16;
    return c.f;
}

__device__ __forceinline__ void gload_lds16(const void* g, void* l) {
    __builtin_amdgcn_global_load_lds(
        (const __attribute__((address_space(1))) void*)g,
        (__attribute__((address_space(3))) void*)l, 16, 0, 0);
}

// ---------------------------------------------------------------------------
// bf16 MFMA GEMM: C[M][N] = A[M][K] @ BT[N][K]^T  (+ epilogue)
// Tile BM x 128, BK=32, 256 threads (4 waves, 2x2).  A has row stride lda.
// EPI 0: plain fp32 store
// EPI 1: softplus(v + bias[col])
// EPI 2: v - sub[row*ldc + col]
// EPI 3: bf16-only store into bf16out[row*ldc + col]
// FUSE_BC: blocks with blockIdx.x == gridDim.x-1 instead compute
//   bcout[32 rows][32] = A[by*32 .. +32][K] @ WbcT[32][K]^T   (BK=64)
// ---------------------------------------------------------------------------
template<int BM, int EPI, bool FUSE_BC>
__global__ __launch_bounds__(256) void gemm_mfma(
    const short* __restrict__ A, int lda,
    const short* __restrict__ BT,
    float* __restrict__ C, int ldc,
    int M, int Ncols, int K,
    const float* __restrict__ bias,
    const float* __restrict__ sub,
    short* __restrict__ bf16out,
    const short* __restrict__ WbcT,
    float* __restrict__ bcout)
{
    constexpr int RI = BM / 32;          // row frags per wave
    constexpr int AS_SZ = (FUSE_BC && BM * 32 < 2048) ? 2048 : BM * 32;
    __shared__ short As[AS_SZ];          // GEMM: [row][32k]; bc: [32row][64k]
    __shared__ short Bs[128 * 32];       // GEMM: [n][32k]; bc: [32n][64k]

    const int tid = threadIdx.x;
    const int wave = tid >> 6, lane = tid & 63;
    const int kk = (lane >> 4) * 8;
    const int r16 = lane & 15;
    const int wr = wave >> 1, wc = wave & 1;

    if (FUSE_BC && blockIdx.x == gridDim.x - 1) {
        // ---- bc path: 32 rows x 32 cols, BK=64 ----
        const int bm2 = blockIdx.y * 32;
        f32x4 acc2 = {};
        for (int k0 = 0; k0 < K; k0 += 64) {
            int off = tid * 16;
            int row = off >> 7;            // 128B per row (64 bf16)
            int ke  = (off & 127) >> 1;
            gload_lds16(A + (size_t)(bm2 + row) * lda + k0 + ke, (char*)As + off);
            gload_lds16(WbcT + (size_t)row * K + k0 + ke, (char*)Bs + off);
            __syncthreads();
            bf16x8 alo = *(const bf16x8*)&As[(wr * 16 + r16) * 64 + kk];
            bf16x8 ahi = *(const bf16x8*)&As[(wr * 16 + r16) * 64 + kk + 32];
            bf16x8 blo = *(const bf16x8*)&Bs[(wc * 16 + r16) * 64 + kk];
            bf16x8 bhi = *(const bf16x8*)&Bs[(wc * 16 + r16) * 64 + kk + 32];
            acc2 = __builtin_amdgcn_mfma_f32_16x16x32_bf16(alo, blo, acc2, 0, 0, 0);
            acc2 = __builtin_amdgcn_mfma_f32_16x16x32_bf16(ahi, bhi, acc2, 0, 0, 0);
            __syncthreads();
        }
        #pragma unroll
        for (int g = 0; g < 4; g++) {
            int row = bm2 + wr * 16 + (lane >> 4) * 4 + g;
            int col = wc * 16 + r16;
            bcout[(size_t)row * 32 + col] = acc2[g];
        }
        return;
    }

    const int bm = blockIdx.y * BM, bn = blockIdx.x * 128;
    f32x4 acc[RI][4] = {};

    for (int k0 = 0; k0 < K; k0 += 32) {
        // stage B tile: 8192B, 2 x 16B per thread
        #pragma unroll
        for (int it = 0; it < 2; it++) {
            int off = it * 4096 + tid * 16;
            int row = off >> 6;             // 64B per row (32 bf16)
            int ke  = (off & 63) >> 1;
            gload_lds16(BT + (size_t)(bn + row) * K + k0 + ke, (char*)Bs + off);
        }
        // stage A tile: BM*64 bytes
        if (tid < BM * 4) {
            int off = tid * 16;
            int row = off >> 6;
            int ke  = (off & 63) >> 1;
            gload_lds16(A + (size_t)(bm + row) * lda + k0 + ke, (char*)As + off);
        }
        __syncthreads();

        bf16x8 a[RI], b[4];
        #pragma unroll
        for (int i = 0; i < RI; i++)
            a[i] = *(const bf16x8*)&As[(wr * (BM / 2) + i * 16 + r16) * 32 + kk];
        #pragma unroll
        for (int j = 0; j < 4; j++)
            b[j] = *(const bf16x8*)&Bs[(wc * 64 + j * 16 + r16) * 32 + kk];
        #pragma unroll
        for (int i = 0; i < RI; i++)
            #pragma unroll
            for (int j = 0; j < 4; j++)
                acc[i][j] = __builtin_amdgcn_mfma_f32_16x16x32_bf16(
                    a[i], b[j], acc[i][j], 0, 0, 0);
        __syncthreads();
    }

    // epilogue: C/D layout col = lane&15, row = (lane>>4)*4 + reg (m89/m91)
    #pragma unroll
    for (int i = 0; i < RI; i++) {
        #pragma unroll
        for (int j = 0; j < 4; j++) {
            #pragma unroll
            for (int g = 0; g < 4; g++) {
                int row = bm + wr * (BM / 2) + i * 16 + (lane >> 4) * 4 + g;
                int col = bn + wc * 64 + j * 16 + r16;
                float v = acc[i][j][g];
                if (EPI == 3) {
                    bf16out[(size_t)row * ldc + col] = f2bf(v);
                } else {
                    if (EPI == 1) {
                        v += bias[col];
                        v = fmaxf(v, 0.f) + log1pf(__expf(-fabsf(v)));
                    }
                    if (EPI == 2) {
                        v -= sub[(size_t)row * ldc + col];
                    }
                    C[(size_t)row * ldc + col] = v;
                }
            }
        }
    }
}

// ---------------------------------------------------------------------------
// 32x32 fp32->bf16 transpose tile (shared helper for prep kernel)
// ---------------------------------------------------------------------------
__device__ __forceinline__ void tr_tile(
    const float* __restrict__ W, short* __restrict__ WT,
    int K, int N, int k0, int n0, int tid)
{
    __shared__ float t[32][33];
    int r = tid >> 3, q = tid & 7;
    float4 v = *(const float4*)&W[(size_t)(k0 + r) * N + n0 + q * 4];
    t[r][q * 4 + 0] = v.x; t[r][q * 4 + 1] = v.y;
    t[r][q * 4 + 2] = v.z; t[r][q * 4 + 3] = v.w;
    __syncthreads();
    short4 o = { f2bf(t[q * 4 + 0][r]), f2bf(t[q * 4 + 1][r]),
                 f2bf(t[q * 4 + 2][r]), f2bf(t[q * 4 + 3][r]) };
    *(short4*)&WT[(size_t)(n0 + r) * K + k0 + q * 4] = o;
}

// ---------------------------------------------------------------------------
// One-shot prep: all fp32->bf16 converts/transposes in a single launch.
// blocks [0,2048): H->Hb        [2048,4096): W_xz^T   [4096,5120): W_dt^T
// [5120,6144): W_out^T          [6144,6272): W_B|W_C pack
// ---------------------------------------------------------------------------
__global__ __launch_bounds__(256) void prep_all(
    const float* __restrict__ H,    short* __restrict__ Hb,
    const float* __restrict__ W_xz, short* __restrict__ WxzT,
    const float* __restrict__ W_dt, short* __restrict__ WdtT,
    const float* __restrict__ W_out,short* __restrict__ WoutT,
    const float* __restrict__ W_B,  const float* __restrict__ W_C,
    short* __restrict__ WbcT)
{
    int bid = blockIdx.x, tid = threadIdx.x;
    if (bid < 2048) {
        int i = bid * 1024 + tid * 4;
        float4 v = *(const float4*)&H[i];
        short4 o = { f2bf(v.x), f2bf(v.y), f2bf(v.z), f2bf(v.w) };
        *(short4*)&Hb[i] = o;
    } else if (bid < 4096) {
        int t = bid - 2048;                       // 64 n-tiles x 32 k-tiles
        tr_tile(W_xz, WxzT, DD, 2 * DD, (t >> 6) * 32, (t & 63) * 32, tid);
    } else if (bid < 5120) {
        int t = bid - 4096;
        tr_tile(W_dt, WdtT, DD, DD, (t >> 5) * 32, (t & 31) * 32, tid);
    } else if (bid < 6144) {
        int t = bid - 5120;
        tr_tile(W_out, WoutT, DD, DD, (t >> 5) * 32, (t & 31) * 32, tid);
    } else {
        int g = (bid - 6144) * 256 + tid;         // 0..32767
        int k = g & (DD - 1);
        int n = g >> 10;
        float v = (n < 16) ? W_B[(size_t)k * NN + n]
                           : W_C[(size_t)k * NN + n - 16];
        WbcT[(size_t)n * DD + k] = f2bf(v);
    }
}

// ---------------------------------------------------------------------------
// Fused 3-phase scan + spike/silu epilogue, one launch.
// Block: 512 threads = 8 d-lanes x 64 chunks.  Grid: (DD/8, BB).
// Phase 1: local chunk scans (s0=0) -> Ls/Sd in LDS.
// Phase 2: inter-chunk combine (128 threads), Sinit written in-place into Ls.
// Phase 3: replay with correct init; g = y*spike*silu(z) stored bf16.
// ---------------------------------------------------------------------------
__global__ __launch_bounds__(512) void scan_fused(
    const short* __restrict__ xzb,    // [2048][2048] bf16 (x | z)
    const float* __restrict__ dtb,    // [2048][1024] fp32 (post-softplus)
    const float* __restrict__ bc,     // [2048][32] fp32 (Bm | Cm)
    const float* __restrict__ A_log,  // [1024][16]
    const float* __restrict__ D_skip,
    const float* __restrict__ v_th,
    short* __restrict__ gout)         // [2048][1024] bf16
{
    __shared__ float Ls[8][NCH][NN];  // 32 KB: local states, then Sinit in-place
    __shared__ float Sd[8][NCH];      // 2 KB: per-chunk sum(dt)

    const int tid = threadIdx.x;
    const int dl = tid & 7;           // d within slice
    const int c  = tid >> 3;          // chunk 0..63
    const int d  = blockIdx.x * 8 + dl;
    const int b  = blockIdx.y;
    const int r0 = b * TT + c * LCH;

    float a2[NN];
    #pragma unroll
    for (int n = 0; n < NN; n++)
        a2[n] = -__expf(A_log[(size_t)d * NN + n]) * L2E;

    // ---- phase 1 ----
    float s[NN];
    #pragma unroll
    for (int n = 0; n < NN; n++) s[n] = 0.f;
    float sum_dt = 0.f;

    for (int j = 0; j < LCH; j++) {
        int r = r0 + j;
        float dt = dtb[(size_t)r * DD + d];
        float x  = bf2f(xzb[(size_t)r * (2 * DD) + d]);
        float dtx = dt * x;
        sum_dt += dt;
        float bB[NN];
        *(float4*)&bB[0]  = *(const float4*)&bc[(size_t)r * 32 + 0];
        *(float4*)&bB[4]  = *(const float4*)&bc[(size_t)r * 32 + 4];
        *(float4*)&bB[8]  = *(const float4*)&bc[(size_t)r * 32 + 8];
        *(float4*)&bB[12] = *(const float4*)&bc[(size_t)r * 32 + 12];
        #pragma unroll
        for (int n = 0; n < NN; n++) {
            float dec = exp2f(a2[n] * dt);
            s[n] = fmaf(dec, s[n], dtx * bB[n]);
        }
    }
    #pragma unroll
    for (int n = 0; n < NN; n++) Ls[dl][c][n] = s[n];
    Sd[dl][c] = sum_dt;
    __syncthreads();

    // ---- phase 2: combine chunk boundaries (in-place Sinit) ----
    if (tid < 128) {
        int dl2 = tid >> 4, n2 = tid & 15;
        float a2n = -__expf(A_log[(size_t)(blockIdx.x * 8 + dl2) * NN + n2]) * L2E;
        float ss = 0.f;
        for (int cc = 0; cc < NCH; cc++) {
            float P = exp2f(a2n * Sd[dl2][cc]);
            float L = Ls[dl2][cc][n2];
            Ls[dl2][cc][n2] = ss;       // Sinit overwrites Lst (read-first)
            ss = fmaf(P, ss, L);
        }
    }
    __syncthreads();

    // ---- phase 3: replay with correct init + epilogue ----
    #pragma unroll
    for (int n = 0; n < NN; n++) s[n] = Ls[dl][c][n];

    float dsk = D_skip[d];
    float vth = fmaxf(v_th[d], V_TH_MIN);

    for (int j = 0; j < LCH; j++) {
        int r = r0 + j;
        float dt = dtb[(size_t)r * DD + d];
        float x  = bf2f(xzb[(size_t)r * (2 * DD) + d]);
        float z  = bf2f(xzb[(size_t)r * (2 * DD) + DD + d]);
        float dtx = dt * x;
        float bB[NN], bC[NN];
        *(float4*)&bB[0]  = *(const float4*)&bc[(size_t)r * 32 + 0];
        *(float4*)&bB[4]  = *(const float4*)&bc[(size_t)r * 32 + 4];
        *(float4*)&bB[8]  = *(const float4*)&bc[(size_t)r * 32 + 8];
        *(float4*)&bB[12] = *(const float4*)&bc[(size_t)r * 32 + 12];
        *(float4*)&bC[0]  = *(const float4*)&bc[(size_t)r * 32 + 16];
        *(float4*)&bC[4]  = *(const float4*)&bc[(size_t)r * 32 + 20];
        *(float4*)&bC[8]  = *(const float4*)&bc[(size_t)r * 32 + 24];
        *(float4*)&bC[12] = *(const float4*)&bc[(size_t)r * 32 + 28];
        float y = 0.f;
        #pragma unroll
        for (int n = 0; n < NN; n++) {
            float dec = exp2f(a2[n] * dt);
            s[n] = fmaf(dec, s[n], dtx * bB[n]);
            y = fmaf(s[n], bC[n], y);
        }
        y = fmaf(dsk, x, y);
        float sp = 1.f / (1.f + __expf(-K_STEEP * (y - vth)));
        float sz = z / (1.f + __expf(-z));
        gout[(size_t)r * DD + d] = f2bf(y * sp * sz);
    }
}

// ---------------------------------------------------------------------------
extern "C" void kernel_launch(void* const* d_in, const int* in_sizes, int n_in,
                              void* d_out, int out_size, void* d_ws, size_t ws_size,
                              hipStream_t stream) {
    const float* H      = (const float*)d_in[0];   // (2,1024,1024)
    const float* W_xz   = (const float*)d_in[1];   // (1024,2048)
    const float* W_dt   = (const float*)d_in[2];   // (1024,1024)
    const float* b_dt   = (const float*)d_in[3];   // (1024,)
    const float* A_log  = (const float*)d_in[4];   // (1024,16)
    const float* W_B    = (const float*)d_in[5];   // (1024,16)
    const float* W_C    = (const float*)d_in[6];   // (1024,16)
    const float* D_skip = (const float*)d_in[7];   // (1024,)
    const float* W_out  = (const float*)d_in[8];   // (1024,1024)
    const float* v_th   = (const float*)d_in[9];   // (1024,)
    float* out = (float*)d_out;

    // flat ws layout (~34 MB of 268 MB) — no aliasing
    float* ws  = (float*)d_ws;
    float* dtb = ws;                   // 2097152 f
    float* bcb = dtb + 2097152;        // 65536 f
    short* p16   = (short*)(bcb + 65536);
    short* xzb   = p16;                // 4194304 s  (bf16 x|z)
    short* Hb    = xzb   + 4194304;    // 2097152 s
    short* WxzT  = Hb    + 2097152;    // 2097152 s
    short* WdtT  = WxzT  + 2097152;    // 1048576 s
    short* WoutT = WdtT  + 1048576;    // 1048576 s
    short* WbcT  = WoutT + 1048576;    // 32768 s
    short* gb    = WbcT  + 32768;      // 2097152 s

    const int M = BB * TT;  // 2048

    // 0) all converts in one launch
    prep_all<<<6272, 256, 0, stream>>>(
        H, Hb, W_xz, WxzT, W_dt, WdtT, W_out, WoutT, W_B, W_C, WbcT);
    // 1) xz = H @ W_xz (bf16 store) with bc fused as extra grid column
    gemm_mfma<32, 3, true><<<dim3(17, M / 32), 256, 0, stream>>>(
        Hb, DD, WxzT, nullptr, 2 * DD, M, 2 * DD, DD,
        nullptr, nullptr, xzb, WbcT, bcb);
    // 2) dt = softplus(x @ W_dt + b_dt)  (A = x-half of xzb, lda = 2048)
    gemm_mfma<32, 1, false><<<dim3(8, M / 32), 256, 0, stream>>>(
        xzb, 2 * DD, WdtT, dtb, DD, M, DD, DD,
        b_dt, nullptr, nullptr, nullptr, nullptr);
    // 3) fused chunked scan + gate epilogue (single launch)
    scan_fused<<<dim3(DD / 8, BB), 512, 0, stream>>>(
        xzb, dtb, bcb, A_log, D_skip, v_th, gb);
    // 4) out = g @ W_out - H
    gemm_mfma<32, 2, false><<<dim3(8, M / 32), 256, 0, stream>>>(
        gb, DD, WoutT, out, DD, M, DD, DD,
        nullptr, H, nullptr, nullptr, nullptr);
}